// Round 12
// baseline (539.990 us; speedup 1.0000x reference)
//
#include <hip/hip_runtime.h>
#include <hip/hip_bf16.h>
#include <math.h>

#define B_ 64
#define N_ 1024
#define E_ 524288
#define K1_ 512
#define K2_ 256
#define K3_ 128
#define M0_ 65536
#define M1_ 32768
#define M2_ 16384
#define M3_ 8192

static __device__ __forceinline__ float eluf(float x){ return x > 0.f ? x : expm1f(x); }
static __device__ __forceinline__ float4 elu4(float4 v){
  float4 o; o.x=eluf(v.x); o.y=eluf(v.y); o.z=eluf(v.z); o.w=eluf(v.w); return o;
}

// Tiled GEMM (round-9 proven schedule). MODE 0: H = X@W. MODE 1: fused top-k
// pool staging H = elu(X[perm[m]]*vals[m]) @ W.
template<int BM,int BN,int MODE>
__global__ __launch_bounds__(256) void k_mm(const float* __restrict__ X,
    const float* __restrict__ W, float* __restrict__ H, int M, int K, int N,
    const int* __restrict__ perm, const float* __restrict__ vals){
  constexpr int TX = BN/4;
  constexpr int TY = 256/TX;
  constexpr int RM = BM/TY;
  __shared__ float Xs[BM][36];
  __shared__ float Ws[32][BN];
  const int t = threadIdx.x;
  const int tx = t % TX, ty = t / TX;
  const int m0 = blockIdx.x*BM, n0 = blockIdx.y*BN;
  float acc[RM][4];
  #pragma unroll
  for (int r=0;r<RM;++r){acc[r][0]=0.f;acc[r][1]=0.f;acc[r][2]=0.f;acc[r][3]=0.f;}
  for (int k0=0;k0<K;k0+=32){
    #pragma unroll
    for (int l=0;l<BM/32;++l){
      int fi=l*256+t, row=fi>>3, q=fi&7;
      int m = m0+row;
      int c4 = (k0>>2)+q;
      float4 v;
      if (MODE==0){
        v = *(const float4*)(X + (size_t)m*K + (c4<<2));
      } else {
        int pm = perm[m]; float vv = vals[m];
        float4 h = *(const float4*)(X + (size_t)pm*K + (c4<<2));
        v.x=eluf(h.x*vv); v.y=eluf(h.y*vv); v.z=eluf(h.z*vv); v.w=eluf(h.w*vv);
      }
      *(float4*)(&Xs[row][q*4]) = v;
    }
    #pragma unroll
    for (int l=0;l<BN/32;++l){
      int fi=l*256+t, wrow=fi/(BN/4), wq=fi%(BN/4);
      *(float4*)(&Ws[wrow][wq*4]) = *(const float4*)(W + (size_t)(k0+wrow)*N + n0 + wq*4);
    }
    __syncthreads();
    #pragma unroll
    for (int kq=0;kq<32;kq+=4){
      float4 xv[RM];
      #pragma unroll
      for (int r=0;r<RM;++r) xv[r] = *(const float4*)(&Xs[ty*RM+r][kq]);
      #pragma unroll
      for (int j=0;j<4;++j){
        float4 wv = *(const float4*)(&Ws[kq+j][tx*4]);
        #pragma unroll
        for (int r=0;r<RM;++r){
          float xs = (j==0)?xv[r].x:(j==1)?xv[r].y:(j==2)?xv[r].z:xv[r].w;
          acc[r][0]=fmaf(xs,wv.x,acc[r][0]);
          acc[r][1]=fmaf(xs,wv.y,acc[r][1]);
          acc[r][2]=fmaf(xs,wv.z,acc[r][2]);
          acc[r][3]=fmaf(xs,wv.w,acc[r][3]);
        }
      }
    }
    __syncthreads();
  }
  #pragma unroll
  for (int r=0;r<RM;++r){
    int m = m0 + ty*RM + r;
    float4 h; h.x=acc[r][0];h.y=acc[r][1];h.z=acc[r][2];h.w=acc[r][3];
    *(float4*)(H + (size_t)m*N + n0 + tx*4) = h;
  }
}

// Decoder GEMM with INLINE unpool: left half of the concat row is computed
// on the fly = elu(elu(gcn-normalize(Hp))) through the rm filter — x7/x9/x11
// are never materialized (saves a 16MB HBM round-trip per layer).
template<int BM,int BN>
__global__ __launch_bounds__(256) void k_mm3(const float* __restrict__ Xskip,
    const float* __restrict__ W, float* __restrict__ H, int M, int K, int N,
    const int* __restrict__ origC,   // cur row -> level-0 (nullptr = identity)
    const int* __restrict__ rmN,     // level-0 -> deeper id (or -1)
    const int* __restrict__ origP,   // deeper id -> level-0
    const int* __restrict__ rmP,     // level-0 -> deeper id (neighbor filter)
    const float* __restrict__ dinvP, const float* __restrict__ Hp,
    const float* __restrict__ bp,
    const int* __restrict__ rowptr0, const int* __restrict__ col0,
    int WD4, int NP){
  constexpr int TX = BN/4;
  constexpr int TY = 256/TX;
  constexpr int RM = BM/TY;
  __shared__ float Xs[BM][36];
  __shared__ float Ws[32][BN];
  const int t = threadIdx.x;
  const int tx = t % TX, ty = t / TX;
  const int m0 = blockIdx.x*BM, n0 = blockIdx.y*BN;
  float acc[RM][4];
  #pragma unroll
  for (int r=0;r<RM;++r){acc[r][0]=0.f;acc[r][1]=0.f;acc[r][2]=0.f;acc[r][3]=0.f;}
  for (int k0=0;k0<K;k0+=32){
    #pragma unroll
    for (int l=0;l<BM/32;++l){
      int fi=l*256+t, row=fi>>3, q=fi&7;
      int m = m0+row;
      int c4 = (k0>>2)+q;
      float4 v; v.x=0.f;v.y=0.f;v.z=0.f;v.w=0.f;
      if (c4 < WD4){
        int o = origC ? origC[m] : m;
        int j = rmN[o];
        if (j>=0){
          int oj = origP[j];
          int beg=rowptr0[oj], end=rowptr0[oj+1];
          float4 a; a.x=0.f;a.y=0.f;a.z=0.f;a.w=0.f;
          for (int e=beg;e<end;++e){
            int s = rmP[col0[e]];
            if (s>=0){
              float c = dinvP[s];
              float4 h = *(const float4*)(Hp + (size_t)s*NP + (c4<<2));
              a.x=fmaf(c,h.x,a.x); a.y=fmaf(c,h.y,a.y);
              a.z=fmaf(c,h.z,a.z); a.w=fmaf(c,h.w,a.w);
            }
          }
          float dn = dinvP[j]; float sc = 2.f*dn*dn;
          float4 hj = *(const float4*)(Hp + (size_t)j*NP + (c4<<2));
          float4 bv = *(const float4*)(bp + (c4<<2));
          v.x = eluf(eluf(fmaf(sc,hj.x,fmaf(dn,a.x,bv.x))));
          v.y = eluf(eluf(fmaf(sc,hj.y,fmaf(dn,a.y,bv.y))));
          v.z = eluf(eluf(fmaf(sc,hj.z,fmaf(dn,a.z,bv.z))));
          v.w = eluf(eluf(fmaf(sc,hj.w,fmaf(dn,a.w,bv.w))));
        }
      } else {
        int ws4 = (K>>2) - WD4;
        v = elu4(*(const float4*)(Xskip + ((size_t)m*ws4 + (c4-WD4))*4));
      }
      *(float4*)(&Xs[row][q*4]) = v;
    }
    #pragma unroll
    for (int l=0;l<BN/32;++l){
      int fi=l*256+t, wrow=fi/(BN/4), wq=fi%(BN/4);
      *(float4*)(&Ws[wrow][wq*4]) = *(const float4*)(W + (size_t)(k0+wrow)*N + n0 + wq*4);
    }
    __syncthreads();
    #pragma unroll
    for (int kq=0;kq<32;kq+=4){
      float4 xv[RM];
      #pragma unroll
      for (int r=0;r<RM;++r) xv[r] = *(const float4*)(&Xs[ty*RM+r][kq]);
      #pragma unroll
      for (int j=0;j<4;++j){
        float4 wv = *(const float4*)(&Ws[kq+j][tx*4]);
        #pragma unroll
        for (int r=0;r<RM;++r){
          float xs = (j==0)?xv[r].x:(j==1)?xv[r].y:(j==2)?xv[r].z:xv[r].w;
          acc[r][0]=fmaf(xs,wv.x,acc[r][0]);
          acc[r][1]=fmaf(xs,wv.y,acc[r][1]);
          acc[r][2]=fmaf(xs,wv.z,acc[r][2]);
          acc[r][3]=fmaf(xs,wv.w,acc[r][3]);
        }
      }
    }
    __syncthreads();
  }
  #pragma unroll
  for (int r=0;r<RM;++r){
    int m = m0 + ty*RM + r;
    float4 h; h.x=acc[r][0];h.y=acc[r][1];h.z=acc[r][2];h.w=acc[r][3];
    *(float4*)(H + (size_t)m*N + n0 + tx*4) = h;
  }
}

// ---- level-0 CSR build (spread atomics only) ----
__global__ void k_deg0(const int* __restrict__ dst, int* __restrict__ degi){
  int i = blockIdx.x*256+threadIdx.x; if (i>=E_) return;
  atomicAdd(&degi[dst[i]], 1);
}
__global__ void k_place0(const int* __restrict__ src, const int* __restrict__ dst,
                         int* __restrict__ cursor, int* __restrict__ col){
  int i = blockIdx.x*256+threadIdx.x; if (i>=E_) return;
  int p = atomicAdd(&cursor[dst[i]], 1);
  col[p] = src[i];
}

// ---- hierarchical scan over M0 degrees ----
__global__ __launch_bounds__(256) void k_scanA(const int* __restrict__ degi,
                                               int* __restrict__ bsum){
  __shared__ int ls[256];
  int b = blockIdx.x, t = threadIdx.x;
  ls[t] = degi[b*256+t]; __syncthreads();
  for (int o=128;o>0;o>>=1){ if (t<o) ls[t]+=ls[t+o]; __syncthreads(); }
  if (t==0) bsum[b] = ls[0];
}
__global__ __launch_bounds__(256) void k_scanB(int* __restrict__ bsum){
  __shared__ int ps[256];
  int t = threadIdx.x;
  ps[t] = bsum[t]; __syncthreads();
  for (int o=1;o<256;o<<=1){
    int v = (t>=o) ? ps[t-o] : 0;
    __syncthreads(); ps[t]+=v; __syncthreads();
  }
  bsum[t] = ps[t];
}
__global__ __launch_bounds__(256) void k_scanC(const int* __restrict__ degi,
    const int* __restrict__ bsum, int* __restrict__ rowptr,
    int* __restrict__ cursor, float* __restrict__ dinv){
  __shared__ int ps[256];
  int b = blockIdx.x, t = threadIdx.x;
  int i = b*256+t;
  int d = degi[i];
  ps[t] = d; __syncthreads();
  for (int o=1;o<256;o<<=1){
    int v = (t>=o) ? ps[t-o] : 0;
    __syncthreads(); ps[t]+=v; __syncthreads();
  }
  int off = (b==0 ? 0 : bsum[b-1]) + ps[t] - d;
  rowptr[i] = off; cursor[i] = off;
  dinv[i] = rsqrtf((float)d + 2.f);
  if (i == M0_-1) rowptr[M0_] = off + d;
}

// pool bookkeeping: origL[i] = prevOrig[idxL[i]]; rm[origL[i]] = i
__global__ void k_book(const int* __restrict__ prevOrig, const int* __restrict__ idxL,
                       int* __restrict__ origL, int* __restrict__ rm, int n){
  int i = blockIdx.x*256+threadIdx.x; if (i>=n) return;
  int o = prevOrig ? prevOrig[idxL[i]] : idxL[i];
  origL[i] = o; rm[o] = i;
}

// pooled-level degree via rm-filtered level-0 CSR
__global__ void k_deg_orig(const int* __restrict__ orig, const int* __restrict__ rowptr0,
                           const int* __restrict__ col0, const int* __restrict__ rm,
                           float* __restrict__ dinv, int M){
  int i = blockIdx.x*256+threadIdx.x; if (i>=M) return;
  int o = orig[i];
  int beg = rowptr0[o], end = rowptr0[o+1];
  int d = 0;
  for (int j=beg;j<end;++j) d += (rm[col0[j]] >= 0) ? 1 : 0;
  dinv[i] = rsqrtf((float)d + 2.f);
}

// ---- level-0 GCN aggregation; optional fused pool-score
template<int F, bool SCORE>
__global__ __launch_bounds__(256) void k_gather(const int* __restrict__ rowptr,
    const int* __restrict__ col, const float* __restrict__ dinv,
    const float* __restrict__ H, const float* __restrict__ bias,
    float* __restrict__ OUT, int M,
    const float* __restrict__ p, float* __restrict__ score){
  constexpr int FQ = F/4;
  int i = blockIdx.x*256+threadIdx.x;
  if (i >= M*FQ) return;
  int n = i/FQ, q = i - (i/FQ)*FQ;
  int beg = rowptr[n], end = rowptr[n+1];
  float4 acc; acc.x=0.f;acc.y=0.f;acc.z=0.f;acc.w=0.f;
  for (int j=beg;j<end;++j){
    int s = col[j];
    float c = dinv[s];
    float4 h = *(const float4*)(H + (size_t)s*F + q*4);
    acc.x=fmaf(c,h.x,acc.x); acc.y=fmaf(c,h.y,acc.y);
    acc.z=fmaf(c,h.z,acc.z); acc.w=fmaf(c,h.w,acc.w);
  }
  float dn = dinv[n];
  float sc = 2.f*dn*dn;
  float4 hn = *(const float4*)(H + (size_t)n*F + q*4);
  float4 bv = *(const float4*)(bias + q*4);
  float4 o;
  o.x = eluf(fmaf(sc,hn.x,fmaf(dn,acc.x,bv.x)));
  o.y = eluf(fmaf(sc,hn.y,fmaf(dn,acc.y,bv.y)));
  o.z = eluf(fmaf(sc,hn.z,fmaf(dn,acc.z,bv.z)));
  o.w = eluf(fmaf(sc,hn.w,fmaf(dn,acc.w,bv.w)));
  *(float4*)(OUT + (size_t)n*F + q*4) = o;
  if (SCORE){
    float4 pv = *(const float4*)(p + q*4);
    float dot = o.x*pv.x + o.y*pv.y + o.z*pv.z + o.w*pv.w;
    float n2  = pv.x*pv.x + pv.y*pv.y + pv.z*pv.z + pv.w*pv.w;
    #pragma unroll
    for (int mk=FQ>>1; mk>0; mk>>=1){
      dot += __shfl_xor(dot, mk);
      n2  += __shfl_xor(n2,  mk);
    }
    if (q==0) score[n] = tanhf(dot * rsqrtf(n2));
  }
}

// ---- pooled-level GCN aggregation through rm filter; optional fused score
template<int F, bool SCORE>
__global__ __launch_bounds__(256) void k_gather_rm(const int* __restrict__ orig,
    const int* __restrict__ rowptr0, const int* __restrict__ col0,
    const int* __restrict__ rm, const float* __restrict__ dinv,
    const float* __restrict__ H, const float* __restrict__ bias,
    float* __restrict__ OUT, int M,
    const float* __restrict__ p, float* __restrict__ score){
  constexpr int FQ = F/4;
  int i = blockIdx.x*256+threadIdx.x;
  if (i >= M*FQ) return;
  int n = i/FQ, q = i - (i/FQ)*FQ;
  int o = orig[n];
  int beg = rowptr0[o], end = rowptr0[o+1];
  float4 acc; acc.x=0.f;acc.y=0.f;acc.z=0.f;acc.w=0.f;
  for (int j=beg;j<end;++j){
    int s = rm[col0[j]];
    if (s >= 0){
      float c = dinv[s];
      float4 h = *(const float4*)(H + (size_t)s*F + q*4);
      acc.x=fmaf(c,h.x,acc.x); acc.y=fmaf(c,h.y,acc.y);
      acc.z=fmaf(c,h.z,acc.z); acc.w=fmaf(c,h.w,acc.w);
    }
  }
  float dn = dinv[n];
  float sc = 2.f*dn*dn;
  float4 hn = *(const float4*)(H + (size_t)n*F + q*4);
  float4 bv = *(const float4*)(bias + q*4);
  float4 ov;
  ov.x = eluf(fmaf(sc,hn.x,fmaf(dn,acc.x,bv.x)));
  ov.y = eluf(fmaf(sc,hn.y,fmaf(dn,acc.y,bv.y)));
  ov.z = eluf(fmaf(sc,hn.z,fmaf(dn,acc.z,bv.z)));
  ov.w = eluf(fmaf(sc,hn.w,fmaf(dn,acc.w,bv.w)));
  *(float4*)(OUT + (size_t)n*F + q*4) = ov;
  if (SCORE){
    float4 pv = *(const float4*)(p + q*4);
    float dot = ov.x*pv.x + ov.y*pv.y + ov.z*pv.z + ov.w*pv.w;
    float n2  = pv.x*pv.x + pv.y*pv.y + pv.z*pv.z + pv.w*pv.w;
    #pragma unroll
    for (int mk=FQ>>1; mk>0; mk>>=1){
      dot += __shfl_xor(dot, mk);
      n2  += __shfl_xor(n2,  mk);
    }
    if (q==0) score[n] = tanhf(dot * rsqrtf(n2));
  }
}

// block g sorts its npg scores descending (tie: lower index first), writes top-K
__global__ void k_topk(const float* __restrict__ score, int npg, int K,
                       int* __restrict__ perm, float* __restrict__ vals){
  __shared__ float ss[1024]; __shared__ int si[1024];
  int g = blockIdx.x, tid = threadIdx.x;
  ss[tid] = score[g*npg + tid]; si[tid] = tid;
  __syncthreads();
  for (int k=2;k<=npg;k<<=1){
    for (int j=k>>1;j>0;j>>=1){
      int ixj = tid ^ j;
      if (ixj > tid){
        float s1=ss[tid], s2=ss[ixj]; int i1=si[tid], i2=si[ixj];
        bool aAfterB = (s1 < s2) || (s1==s2 && i1 > i2);
        bool sw = ((tid & k)==0) ? aAfterB : !aAfterB;
        if (sw){ ss[tid]=s2; si[tid]=i2; ss[ixj]=s1; si[ixj]=i1; }
      }
      __syncthreads();
    }
  }
  if (tid < K){ perm[g*K+tid] = g*npg + si[tid]; vals[g*K+tid] = ss[tid]; }
}

// per-graph global max/mean pool over (1024,32), then MLP head + log_softmax
__global__ void k_head(const float* __restrict__ x13, const float* __restrict__ Wl,
                       const float* __restrict__ Wc, const float* __restrict__ bc,
                       float* __restrict__ out){
  __shared__ float smax[256], ssum[256];
  __shared__ float gv[64], g2[64], logit[10];
  int g = blockIdx.x, t = threadIdx.x;
  int f = t & 31, r0 = t >> 5;
  float mx = -3.4e38f, sm = 0.f;
  const float* base = x13 + (size_t)g*N_*32;
  for (int r=r0; r<N_; r+=8){ float v = base[r*32+f]; mx = fmaxf(mx,v); sm += v; }
  smax[t]=mx; ssum[t]=sm; __syncthreads();
  if (t<128){ smax[t]=fmaxf(smax[t],smax[t+128]); ssum[t]+=ssum[t+128]; } __syncthreads();
  if (t<64){ smax[t]=fmaxf(smax[t],smax[t+64]); ssum[t]+=ssum[t+64]; } __syncthreads();
  if (t<32){
    float m2 = fmaxf(smax[t],smax[t+32]); float s2 = ssum[t]+ssum[t+32];
    gv[t] = eluf(m2); gv[32+t] = eluf(s2 * (1.f/N_));
  }
  __syncthreads();
  if (t<64){
    float acc=0.f;
    #pragma unroll
    for (int i2=0;i2<64;++i2) acc = fmaf(gv[i2], Wl[i2*64+t], acc);
    g2[t] = eluf(acc);
  }
  __syncthreads();
  if (t<10){
    float acc = bc[t];
    #pragma unroll
    for (int j=0;j<64;++j) acc = fmaf(g2[j], Wc[j*10+t], acc);
    logit[t] = acc;
  }
  __syncthreads();
  if (t==0){
    float m=-3.4e38f; for (int c=0;c<10;++c) m=fmaxf(m,logit[c]);
    float s=0.f; for (int c=0;c<10;++c) s += expf(logit[c]-m);
    float lse = m + logf(s);
    for (int c=0;c<10;++c) out[g*10+c] = logit[c]-lse;
  }
}

extern "C" void kernel_launch(void* const* d_in, const int* in_sizes, int n_in,
                              void* d_out, int out_size, void* d_ws, size_t ws_size,
                              hipStream_t stream){
  const float* x  = (const float*)d_in[0];
  const float* W1 = (const float*)d_in[1];
  const float* b1 = (const float*)d_in[2];
  const float* p1 = (const float*)d_in[3];
  const float* W2 = (const float*)d_in[4];
  const float* b2 = (const float*)d_in[5];
  const float* p2 = (const float*)d_in[6];
  const float* W3 = (const float*)d_in[7];
  const float* b3 = (const float*)d_in[8];
  const float* p3 = (const float*)d_in[9];
  const float* W4 = (const float*)d_in[10];
  const float* b4 = (const float*)d_in[11];
  const float* W5 = (const float*)d_in[12];
  const float* b5 = (const float*)d_in[13];
  const float* W6 = (const float*)d_in[14];
  const float* b6 = (const float*)d_in[15];
  const float* W7 = (const float*)d_in[16];
  const float* b7 = (const float*)d_in[17];
  const float* Wl = (const float*)d_in[18];
  const float* Wc = (const float*)d_in[19];
  const float* bc = (const float*)d_in[20];
  const int* src0 = (const int*)d_in[21];
  const int* dst0 = (const int*)d_in[22];
  float* out = (float*)d_out;

  char* wsp = (char*)d_ws;
  size_t off = 0;
  auto alloc = [&](size_t bytes)->char*{
    char* p = wsp + off;
    off += (bytes + 255) & ~(size_t)255;
    return p;
  };
  float* bufA = (float*)alloc((size_t)2097152*4);   // x1 (alive till mm7)
  float* bufB = (float*)alloc((size_t)2097152*4);   // x3 (alive till mm6)
  float* bufC = (float*)alloc((size_t)2097152*4);   // x5 (till mm5) / x13
  float* Ha   = (float*)alloc((size_t)2097152*4);   // H1-H4 / H6
  float* Hb   = (float*)alloc((size_t)2097152*4);   // H5 / H7
  float* score= (float*)alloc((size_t)M0_*4);
  float* vals2= (float*)alloc((size_t)M1_*4);
  float* vals4= (float*)alloc((size_t)M2_*4);
  float* vals6= (float*)alloc((size_t)M3_*4);
  int* idx2 = (int*)alloc((size_t)M1_*4);   // level2 -> level0
  int* idx4 = (int*)alloc((size_t)M2_*4);   // level4 -> level2
  int* idx6 = (int*)alloc((size_t)M3_*4);   // level6 -> level4
  int* orig4 = (int*)alloc((size_t)M2_*4);  // level4 -> level0
  int* orig6 = (int*)alloc((size_t)M3_*4);  // level6 -> level0
  int* rm02 = (int*)alloc((size_t)M0_*4);
  int* rm04 = (int*)alloc((size_t)M0_*4);
  int* rm06 = (int*)alloc((size_t)M0_*4);
  int* col0 = (int*)alloc((size_t)E_*4);
  int* rowptr0 = (int*)alloc((size_t)(M0_+1)*4);
  int* cursor0 = (int*)alloc((size_t)M0_*4);
  int* degi0 = (int*)alloc((size_t)M0_*4);
  int* bsum  = (int*)alloc((size_t)256*4);
  float* dinv0 = (float*)alloc((size_t)M0_*4);
  float* dinv2 = (float*)alloc((size_t)M1_*4);
  float* dinv4 = (float*)alloc((size_t)M2_*4);
  float* dinv6 = (float*)alloc((size_t)M3_*4);

  auto NB = [](int total){ return (total+255)/256; };

  // ---- level-0 CSR (shared by layers 1 and 7)
  hipMemsetAsync(degi0, 0, (size_t)M0_*4, stream);
  k_deg0<<<NB(E_),256,0,stream>>>(dst0, degi0);
  k_scanA<<<256,256,0,stream>>>(degi0, bsum);
  k_scanB<<<1,256,0,stream>>>(bsum);
  k_scanC<<<256,256,0,stream>>>(degi0, bsum, rowptr0, cursor0, dinv0);
  k_place0<<<NB(E_),256,0,stream>>>(src0, dst0, cursor0, col0);

  // ---- layer 1: H1 = x@W1; x1 = gather (bufA) + score1
  k_mm<128,32,0><<<dim3(M0_/128,1),256,0,stream>>>(x, W1, Ha, M0_, 128, 32, nullptr,nullptr);
  k_gather<32,true><<<NB(M0_*8),256,0,stream>>>(rowptr0, col0, dinv0, Ha, b1, bufA, M0_, p1, score);

  // ---- pool 1
  k_topk<<<B_,1024,0,stream>>>(score, 1024, K1_, idx2, vals2);
  hipMemsetAsync(rm02, 0xFF, (size_t)M0_*4, stream);
  k_book<<<NB(M1_),256,0,stream>>>(nullptr, idx2, idx2, rm02, M1_);
  k_deg_orig<<<NB(M1_),256,0,stream>>>(idx2, rowptr0, col0, rm02, dinv2, M1_);

  // ---- layer 2: H2 = elu(pool(x1))@W2; x3 = gather (bufB) + score2
  k_mm<64,64,1><<<dim3(M1_/64,1),256,0,stream>>>(bufA, W2, Ha, M1_, 32, 64, idx2, vals2);
  k_gather_rm<64,true><<<NB(M1_*16),256,0,stream>>>(idx2, rowptr0, col0, rm02, dinv2, Ha, b2, bufB, M1_, p2, score);

  // ---- pool 2
  k_topk<<<B_,512,0,stream>>>(score, 512, K2_, idx4, vals4);
  hipMemsetAsync(rm04, 0xFF, (size_t)M0_*4, stream);
  k_book<<<NB(M2_),256,0,stream>>>(idx2, idx4, orig4, rm04, M2_);
  k_deg_orig<<<NB(M2_),256,0,stream>>>(orig4, rowptr0, col0, rm04, dinv4, M2_);

  // ---- layer 3: H3 = elu(pool(x3))@W3; x5 = gather (bufC) + score3
  k_mm<64,64,1><<<dim3(M2_/64,2),256,0,stream>>>(bufB, W3, Ha, M2_, 64, 128, idx4, vals4);
  k_gather_rm<128,true><<<NB(M2_*32),256,0,stream>>>(orig4, rowptr0, col0, rm04, dinv4, Ha, b3, bufC, M2_, p3, score);

  // ---- pool 3
  k_topk<<<B_,256,0,stream>>>(score, 256, K3_, idx6, vals6);
  hipMemsetAsync(rm06, 0xFF, (size_t)M0_*4, stream);
  k_book<<<NB(M3_),256,0,stream>>>(orig4, idx6, orig6, rm06, M3_);
  k_deg_orig<<<NB(M3_),256,0,stream>>>(orig6, rowptr0, col0, rm06, dinv6, M3_);

  // ---- layer 4: H4 = elu(pool(x5))@W4   (x7 never materialized)
  k_mm<64,64,1><<<dim3(M3_/64,4),256,0,stream>>>(bufC, W4, Ha, M3_, 128, 256, idx6, vals6);

  // ---- layer 5: H5 = elu(cat(inline-gcn(H4), x5))@W5
  k_mm3<64,64><<<dim3(M2_/64,2),256,0,stream>>>(bufC, W5, Hb, M2_, 384, 128,
      orig4, rm06, orig6, rm06, dinv6, Ha, b4, rowptr0, col0, 64, 256);

  // ---- layer 6: H6 = elu(cat(inline-gcn(H5), x3))@W6
  k_mm3<64,64><<<dim3(M1_/64,1),256,0,stream>>>(bufB, W6, Ha, M1_, 192, 64,
      idx2, rm04, orig4, rm04, dinv4, Hb, b5, rowptr0, col0, 32, 128);

  // ---- layer 7: H7 = elu(cat(inline-gcn(H6), x1))@W7
  k_mm3<64,32><<<dim3(M0_/64,1),256,0,stream>>>(bufA, W7, Hb, M0_, 96, 32,
      nullptr, rm02, idx2, rm02, dinv2, Ha, b6, rowptr0, col0, 16, 64);

  // ---- x13 = gather(H7) (bufC); head
  k_gather<32,false><<<NB(M0_*8),256,0,stream>>>(rowptr0, col0, dinv0, Hb, b7, bufC, M0_, nullptr, nullptr);
  k_head<<<B_,256,0,stream>>>(bufC, Wl, Wc, bc, out);

  (void)in_sizes; (void)n_in; (void)out_size; (void)ws_size;
}

// Round 13
// 402.186 us; speedup vs baseline: 1.3426x; 1.3426x over previous
//
#include <hip/hip_runtime.h>
#include <hip/hip_bf16.h>
#include <math.h>
#include <stdint.h>

#define B_ 64
#define N_ 1024
#define E_ 524288
#define K1_ 512
#define K2_ 256
#define K3_ 128
#define M0_ 65536
#define M1_ 32768
#define M2_ 16384
#define M3_ 8192

static __device__ __forceinline__ float eluf(float x){ return x > 0.f ? x : expm1f(x); }
static __device__ __forceinline__ float4 elu4(float4 v){
  float4 o; o.x=eluf(v.x); o.y=eluf(v.y); o.z=eluf(v.z); o.w=eluf(v.w); return o;
}

#define GLD_LDS16(srcp, dstp) __builtin_amdgcn_global_load_lds( \
    (const __attribute__((address_space(1))) uint32_t*)(srcp), \
    (__attribute__((address_space(3))) uint32_t*)(dstp), 16, 0, 0)

// Tiled GEMM, round-9 schedule, with global_load_lds width-16 staging and
// XOR-swizzled linear LDS (swizzle applied on the GLOBAL source / write slot,
// and on the read slot — both-sides-or-neither).
// MODE 0: H = X@W (X staged via global_load_lds)
// MODE 1: H = elu(X[perm[m]]*vals[m]) @ W  (register-staged, swizzled write)
// MODE 2: H = elu(concat(Xd via rm/orig, Xskip)) @ W (register-staged)
// W tiles ALWAYS staged via global_load_lds.
template<int BM,int BN,int MODE>
__global__ __launch_bounds__(256) void k_mm(const float* __restrict__ X,
    const float* __restrict__ W, float* __restrict__ H, int M, int K, int N,
    const int* __restrict__ perm, const float* __restrict__ vals,
    const float* __restrict__ Xd, const int* __restrict__ orig,
    const int* __restrict__ rm, int WD4){
  constexpr int TX = BN/4;           // 8 or 16
  constexpr int TY = 256/TX;         // 32 or 16
  constexpr int RM = BM/TY;          // 4
  constexpr int SL4 = BN/4;          // W float4-slots per row
  __shared__ float4 Xs4[BM*8];       // [row][c'] c' = c ^ (row&7), linear
  __shared__ float4 Ws4[8*BN];       // [k][c], linear
  const int t = threadIdx.x;
  const int tx = t % TX, ty = t / TX;
  const int w = t>>6, ln = t&63;     // wave id, lane id
  const int m0 = blockIdx.x*BM, n0 = blockIdx.y*BN;
  float acc[RM][4];
  #pragma unroll
  for (int r=0;r<RM;++r){acc[r][0]=0.f;acc[r][1]=0.f;acc[r][2]=0.f;acc[r][3]=0.f;}
  for (int k0=0;k0<K;k0+=32){
    // ---- stage X tile (BM x 32 floats = BM*8 float4 slots)
    if (MODE==0){
      #pragma unroll
      for (int i=0;i<BM/32;++i){
        int sbase = (w*(BM/32)+i)*64;
        int slot = sbase + ln;
        int row = slot>>3, c4 = slot&7;
        int g4 = (k0>>2) + (c4 ^ (row&7));
        const float* src = X + (size_t)(m0+row)*K + (g4<<2);
        GLD_LDS16(src, &Xs4[sbase]);
      }
    } else {
      #pragma unroll
      for (int l=0;l<BM/32;++l){
        int fi=l*256+t, row=fi>>3, q=fi&7;
        int m = m0+row;
        int c4 = (k0>>2)+q;
        float4 v;
        if (MODE==1){
          int pm = perm[m]; float vv = vals[m];
          float4 h = *(const float4*)(X + (size_t)pm*K + (c4<<2));
          v.x=eluf(h.x*vv); v.y=eluf(h.y*vv); v.z=eluf(h.z*vv); v.w=eluf(h.w*vv);
        } else {
          if (c4 < WD4){
            int o = orig ? orig[m] : m;
            int j = rm[o];
            if (j>=0) v = elu4(*(const float4*)(Xd + ((size_t)j*WD4 + c4)*4));
            else { v.x=0.f;v.y=0.f;v.z=0.f;v.w=0.f; }
          } else {
            int ws4 = (K>>2) - WD4;
            v = elu4(*(const float4*)(X + ((size_t)m*ws4 + (c4-WD4))*4));
          }
        }
        Xs4[row*8 + (q ^ (row&7))] = v;
      }
    }
    // ---- stage W tile (32 x BN floats = 8*BN float4 slots), linear
    #pragma unroll
    for (int i=0;i<BN/32;++i){
      int sbase = (w*(BN/32)+i)*64;
      int slot = sbase + ln;
      int wrow = slot/SL4, c = slot%SL4;
      const float* src = W + (size_t)(k0+wrow)*N + n0 + (c<<2);
      GLD_LDS16(src, &Ws4[sbase]);
    }
    __syncthreads();
    #pragma unroll
    for (int kq=0;kq<32;kq+=4){
      const int g = kq>>2;
      float4 xv[RM];
      #pragma unroll
      for (int r=0;r<RM;++r){
        int row = ty + TY*r;
        xv[r] = Xs4[row*8 + (g ^ (row&7))];
      }
      #pragma unroll
      for (int j=0;j<4;++j){
        float4 wv = Ws4[(kq+j)*SL4 + tx];
        #pragma unroll
        for (int r=0;r<RM;++r){
          float xs = (j==0)?xv[r].x:(j==1)?xv[r].y:(j==2)?xv[r].z:xv[r].w;
          acc[r][0]=fmaf(xs,wv.x,acc[r][0]);
          acc[r][1]=fmaf(xs,wv.y,acc[r][1]);
          acc[r][2]=fmaf(xs,wv.z,acc[r][2]);
          acc[r][3]=fmaf(xs,wv.w,acc[r][3]);
        }
      }
    }
    __syncthreads();
  }
  #pragma unroll
  for (int r=0;r<RM;++r){
    int m = m0 + ty + TY*r;
    float4 h; h.x=acc[r][0];h.y=acc[r][1];h.z=acc[r][2];h.w=acc[r][3];
    *(float4*)(H + (size_t)m*N + n0 + tx*4) = h;
  }
}

// ---- level-0 CSR build (spread atomics only) ----
__global__ void k_deg0(const int* __restrict__ dst, int* __restrict__ degi){
  int i = blockIdx.x*256+threadIdx.x; if (i>=E_) return;
  atomicAdd(&degi[dst[i]], 1);
}
__global__ void k_place0(const int* __restrict__ src, const int* __restrict__ dst,
                         int* __restrict__ cursor, int* __restrict__ col){
  int i = blockIdx.x*256+threadIdx.x; if (i>=E_) return;
  int p = atomicAdd(&cursor[dst[i]], 1);
  col[p] = src[i];
}

// ---- hierarchical scan over M0 degrees ----
__global__ __launch_bounds__(256) void k_scanA(const int* __restrict__ degi,
                                               int* __restrict__ bsum){
  __shared__ int ls[256];
  int b = blockIdx.x, t = threadIdx.x;
  ls[t] = degi[b*256+t]; __syncthreads();
  for (int o=128;o>0;o>>=1){ if (t<o) ls[t]+=ls[t+o]; __syncthreads(); }
  if (t==0) bsum[b] = ls[0];
}
__global__ __launch_bounds__(256) void k_scanB(int* __restrict__ bsum){
  __shared__ int ps[256];
  int t = threadIdx.x;
  ps[t] = bsum[t]; __syncthreads();
  for (int o=1;o<256;o<<=1){
    int v = (t>=o) ? ps[t-o] : 0;
    __syncthreads(); ps[t]+=v; __syncthreads();
  }
  bsum[t] = ps[t];
}
__global__ __launch_bounds__(256) void k_scanC(const int* __restrict__ degi,
    const int* __restrict__ bsum, int* __restrict__ rowptr,
    int* __restrict__ cursor, float* __restrict__ dinv){
  __shared__ int ps[256];
  int b = blockIdx.x, t = threadIdx.x;
  int i = b*256+t;
  int d = degi[i];
  ps[t] = d; __syncthreads();
  for (int o=1;o<256;o<<=1){
    int v = (t>=o) ? ps[t-o] : 0;
    __syncthreads(); ps[t]+=v; __syncthreads();
  }
  int off = (b==0 ? 0 : bsum[b-1]) + ps[t] - d;
  rowptr[i] = off; cursor[i] = off;
  dinv[i] = rsqrtf((float)d + 2.f);
  if (i == M0_-1) rowptr[M0_] = off + d;
}

// pooled-level degree via rm-filtered level-0 CSR
__global__ void k_deg_orig(const int* __restrict__ orig, const int* __restrict__ rowptr0,
                           const int* __restrict__ col0, const int* __restrict__ rm,
                           float* __restrict__ dinv, int M){
  int i = blockIdx.x*256+threadIdx.x; if (i>=M) return;
  int o = orig[i];
  int beg = rowptr0[o], end = rowptr0[o+1];
  int d = 0;
  for (int j=beg;j<end;++j) d += (rm[col0[j]] >= 0) ? 1 : 0;
  dinv[i] = rsqrtf((float)d + 2.f);
}

__global__ void k_compose_idx(const int* __restrict__ prevOrig, const int* __restrict__ idxL,
                              int* __restrict__ origL, int n){
  int i = blockIdx.x*256+threadIdx.x; if (i<n) origL[i] = prevOrig[idxL[i]];
}

// ---- level-0 GCN aggregation; optional fused pool-score
template<int F, bool SCORE>
__global__ __launch_bounds__(256) void k_gather(const int* __restrict__ rowptr,
    const int* __restrict__ col, const float* __restrict__ dinv,
    const float* __restrict__ H, const float* __restrict__ bias,
    float* __restrict__ OUT, int M,
    const float* __restrict__ p, float* __restrict__ score){
  constexpr int FQ = F/4;
  int i = blockIdx.x*256+threadIdx.x;
  if (i >= M*FQ) return;
  int n = i/FQ, q = i - (i/FQ)*FQ;
  int beg = rowptr[n], end = rowptr[n+1];
  float4 acc; acc.x=0.f;acc.y=0.f;acc.z=0.f;acc.w=0.f;
  for (int j=beg;j<end;++j){
    int s = col[j];
    float c = dinv[s];
    float4 h = *(const float4*)(H + (size_t)s*F + q*4);
    acc.x=fmaf(c,h.x,acc.x); acc.y=fmaf(c,h.y,acc.y);
    acc.z=fmaf(c,h.z,acc.z); acc.w=fmaf(c,h.w,acc.w);
  }
  float dn = dinv[n];
  float sc = 2.f*dn*dn;
  float4 hn = *(const float4*)(H + (size_t)n*F + q*4);
  float4 bv = *(const float4*)(bias + q*4);
  float4 o;
  o.x = eluf(fmaf(sc,hn.x,fmaf(dn,acc.x,bv.x)));
  o.y = eluf(fmaf(sc,hn.y,fmaf(dn,acc.y,bv.y)));
  o.z = eluf(fmaf(sc,hn.z,fmaf(dn,acc.z,bv.z)));
  o.w = eluf(fmaf(sc,hn.w,fmaf(dn,acc.w,bv.w)));
  *(float4*)(OUT + (size_t)n*F + q*4) = o;
  if (SCORE){
    float4 pv = *(const float4*)(p + q*4);
    float dot = o.x*pv.x + o.y*pv.y + o.z*pv.z + o.w*pv.w;
    float n2  = pv.x*pv.x + pv.y*pv.y + pv.z*pv.z + pv.w*pv.w;
    #pragma unroll
    for (int mk=FQ>>1; mk>0; mk>>=1){
      dot += __shfl_xor(dot, mk);
      n2  += __shfl_xor(n2,  mk);
    }
    if (q==0) score[n] = tanhf(dot * rsqrtf(n2));
  }
}

// ---- pooled-level GCN aggregation through rm filter; optional fused score
template<int F, bool SCORE>
__global__ __launch_bounds__(256) void k_gather_rm(const int* __restrict__ orig,
    const int* __restrict__ rowptr0, const int* __restrict__ col0,
    const int* __restrict__ rm, const float* __restrict__ dinv,
    const float* __restrict__ H, const float* __restrict__ bias,
    float* __restrict__ OUT, int M,
    const float* __restrict__ p, float* __restrict__ score){
  constexpr int FQ = F/4;
  int i = blockIdx.x*256+threadIdx.x;
  if (i >= M*FQ) return;
  int n = i/FQ, q = i - (i/FQ)*FQ;
  int o = orig[n];
  int beg = rowptr0[o], end = rowptr0[o+1];
  float4 acc; acc.x=0.f;acc.y=0.f;acc.z=0.f;acc.w=0.f;
  for (int j=beg;j<end;++j){
    int s = rm[col0[j]];
    if (s >= 0){
      float c = dinv[s];
      float4 h = *(const float4*)(H + (size_t)s*F + q*4);
      acc.x=fmaf(c,h.x,acc.x); acc.y=fmaf(c,h.y,acc.y);
      acc.z=fmaf(c,h.z,acc.z); acc.w=fmaf(c,h.w,acc.w);
    }
  }
  float dn = dinv[n];
  float sc = 2.f*dn*dn;
  float4 hn = *(const float4*)(H + (size_t)n*F + q*4);
  float4 bv = *(const float4*)(bias + q*4);
  float4 ov;
  ov.x = eluf(fmaf(sc,hn.x,fmaf(dn,acc.x,bv.x)));
  ov.y = eluf(fmaf(sc,hn.y,fmaf(dn,acc.y,bv.y)));
  ov.z = eluf(fmaf(sc,hn.z,fmaf(dn,acc.z,bv.z)));
  ov.w = eluf(fmaf(sc,hn.w,fmaf(dn,acc.w,bv.w)));
  *(float4*)(OUT + (size_t)n*F + q*4) = ov;
  if (SCORE){
    float4 pv = *(const float4*)(p + q*4);
    float dot = ov.x*pv.x + ov.y*pv.y + ov.z*pv.z + ov.w*pv.w;
    float n2  = pv.x*pv.x + pv.y*pv.y + pv.z*pv.z + pv.w*pv.w;
    #pragma unroll
    for (int mk=FQ>>1; mk>0; mk>>=1){
      dot += __shfl_xor(dot, mk);
      n2  += __shfl_xor(n2,  mk);
    }
    if (q==0) score[n] = tanhf(dot * rsqrtf(n2));
  }
}

// block g sorts its npg scores descending (tie: lower index first), writes top-K
__global__ void k_topk(const float* __restrict__ score, int npg, int K,
                       int* __restrict__ perm, float* __restrict__ vals){
  __shared__ float ss[1024]; __shared__ int si[1024];
  int g = blockIdx.x, tid = threadIdx.x;
  ss[tid] = score[g*npg + tid]; si[tid] = tid;
  __syncthreads();
  for (int k=2;k<=npg;k<<=1){
    for (int j=k>>1;j>0;j>>=1){
      int ixj = tid ^ j;
      if (ixj > tid){
        float s1=ss[tid], s2=ss[ixj]; int i1=si[tid], i2=si[ixj];
        bool aAfterB = (s1 < s2) || (s1==s2 && i1 > i2);
        bool sw = ((tid & k)==0) ? aAfterB : !aAfterB;
        if (sw){ ss[tid]=s2; si[tid]=i2; ss[ixj]=s1; si[ixj]=i1; }
      }
      __syncthreads();
    }
  }
  if (tid < K){ perm[g*K+tid] = g*npg + si[tid]; vals[g*K+tid] = ss[tid]; }
}

__global__ void k_remap_set(const int* __restrict__ perm, int* __restrict__ remap, int n){
  int i = blockIdx.x*256+threadIdx.x; if (i<n) remap[perm[i]] = i;
}

// per-graph global max/mean pool over (1024,32), then MLP head + log_softmax
__global__ void k_head(const float* __restrict__ x13, const float* __restrict__ Wl,
                       const float* __restrict__ Wc, const float* __restrict__ bc,
                       float* __restrict__ out){
  __shared__ float smax[256], ssum[256];
  __shared__ float gv[64], g2[64], logit[10];
  int g = blockIdx.x, t = threadIdx.x;
  int f = t & 31, r0 = t >> 5;
  float mx = -3.4e38f, sm = 0.f;
  const float* base = x13 + (size_t)g*N_*32;
  for (int r=r0; r<N_; r+=8){ float v = base[r*32+f]; mx = fmaxf(mx,v); sm += v; }
  smax[t]=mx; ssum[t]=sm; __syncthreads();
  if (t<128){ smax[t]=fmaxf(smax[t],smax[t+128]); ssum[t]+=ssum[t+128]; } __syncthreads();
  if (t<64){ smax[t]=fmaxf(smax[t],smax[t+64]); ssum[t]+=ssum[t+64]; } __syncthreads();
  if (t<32){
    float m2 = fmaxf(smax[t],smax[t+32]); float s2 = ssum[t]+ssum[t+32];
    gv[t] = eluf(m2); gv[32+t] = eluf(s2 * (1.f/N_));
  }
  __syncthreads();
  if (t<64){
    float acc=0.f;
    #pragma unroll
    for (int i2=0;i2<64;++i2) acc = fmaf(gv[i2], Wl[i2*64+t], acc);
    g2[t] = eluf(acc);
  }
  __syncthreads();
  if (t<10){
    float acc = bc[t];
    #pragma unroll
    for (int j=0;j<64;++j) acc = fmaf(g2[j], Wc[j*10+t], acc);
    logit[t] = acc;
  }
  __syncthreads();
  if (t==0){
    float m=-3.4e38f; for (int c=0;c<10;++c) m=fmaxf(m,logit[c]);
    float s=0.f; for (int c=0;c<10;++c) s += expf(logit[c]-m);
    float lse = m + logf(s);
    for (int c=0;c<10;++c) out[g*10+c] = logit[c]-lse;
  }
}

extern "C" void kernel_launch(void* const* d_in, const int* in_sizes, int n_in,
                              void* d_out, int out_size, void* d_ws, size_t ws_size,
                              hipStream_t stream){
  const float* x  = (const float*)d_in[0];
  const float* W1 = (const float*)d_in[1];
  const float* b1 = (const float*)d_in[2];
  const float* p1 = (const float*)d_in[3];
  const float* W2 = (const float*)d_in[4];
  const float* b2 = (const float*)d_in[5];
  const float* p2 = (const float*)d_in[6];
  const float* W3 = (const float*)d_in[7];
  const float* b3 = (const float*)d_in[8];
  const float* p3 = (const float*)d_in[9];
  const float* W4 = (const float*)d_in[10];
  const float* b4 = (const float*)d_in[11];
  const float* W5 = (const float*)d_in[12];
  const float* b5 = (const float*)d_in[13];
  const float* W6 = (const float*)d_in[14];
  const float* b6 = (const float*)d_in[15];
  const float* W7 = (const float*)d_in[16];
  const float* b7 = (const float*)d_in[17];
  const float* Wl = (const float*)d_in[18];
  const float* Wc = (const float*)d_in[19];
  const float* bc = (const float*)d_in[20];
  const int* src0 = (const int*)d_in[21];
  const int* dst0 = (const int*)d_in[22];
  float* out = (float*)d_out;

  char* wsp = (char*)d_ws;
  size_t off = 0;
  auto alloc = [&](size_t bytes)->char*{
    char* p = wsp + off;
    off += (bytes + 255) & ~(size_t)255;
    return p;
  };
  float* bufA = (float*)alloc((size_t)2097152*4);   // x1 / x13
  float* bufB = (float*)alloc((size_t)2097152*4);   // x3
  float* bufC = (float*)alloc((size_t)2097152*4);   // x5 / x11
  float* bufD = (float*)alloc((size_t)2097152*4);   // x7 / x9
  float* bufH = (float*)alloc((size_t)2097152*4);   // pre-norm H
  float* score= (float*)alloc((size_t)M0_*4);
  float* vals2= (float*)alloc((size_t)M1_*4);
  float* vals4= (float*)alloc((size_t)M2_*4);
  float* vals6= (float*)alloc((size_t)M3_*4);
  int* idx2 = (int*)alloc((size_t)M1_*4);   // level2 -> level0
  int* idx4 = (int*)alloc((size_t)M2_*4);   // level4 -> level2
  int* idx6 = (int*)alloc((size_t)M3_*4);   // level6 -> level4
  int* orig4 = (int*)alloc((size_t)M2_*4);  // level4 -> level0
  int* orig6 = (int*)alloc((size_t)M3_*4);  // level6 -> level0
  int* rm02 = (int*)alloc((size_t)M0_*4);
  int* rm04 = (int*)alloc((size_t)M0_*4);
  int* rm06 = (int*)alloc((size_t)M0_*4);
  int* col0 = (int*)alloc((size_t)E_*4);
  int* rowptr0 = (int*)alloc((size_t)(M0_+1)*4);
  int* cursor0 = (int*)alloc((size_t)M0_*4);
  int* degi0 = (int*)alloc((size_t)M0_*4);
  int* bsum  = (int*)alloc((size_t)256*4);
  float* dinv0 = (float*)alloc((size_t)M0_*4);
  float* dinv2 = (float*)alloc((size_t)M1_*4);
  float* dinv4 = (float*)alloc((size_t)M2_*4);
  float* dinv6 = (float*)alloc((size_t)M3_*4);

  auto NB = [](int total){ return (total+255)/256; };

  // ---- level-0 CSR (shared by layers 1 and 7)
  hipMemsetAsync(degi0, 0, (size_t)M0_*4, stream);
  k_deg0<<<NB(E_),256,0,stream>>>(dst0, degi0);
  k_scanA<<<256,256,0,stream>>>(degi0, bsum);
  k_scanB<<<1,256,0,stream>>>(bsum);
  k_scanC<<<256,256,0,stream>>>(degi0, bsum, rowptr0, cursor0, dinv0);
  k_place0<<<NB(E_),256,0,stream>>>(src0, dst0, cursor0, col0);

  // ---- layer 1: gcn(x) -> x1 (bufA) + fused score1
  k_mm<128,32,0><<<dim3(M0_/128,1),256,0,stream>>>(x, W1, bufH, M0_, 128, 32,
      nullptr,nullptr,nullptr,nullptr,nullptr,0);
  k_gather<32,true><<<NB(M0_*8),256,0,stream>>>(rowptr0, col0, dinv0, bufH, b1, bufA, M0_, p1, score);

  // ---- pool 1
  k_topk<<<B_,1024,0,stream>>>(score, 1024, K1_, idx2, vals2);
  hipMemsetAsync(rm02, 0xFF, (size_t)M0_*4, stream);
  k_remap_set<<<NB(M1_),256,0,stream>>>(idx2, rm02, M1_);
  k_deg_orig<<<NB(M1_),256,0,stream>>>(idx2, rowptr0, col0, rm02, dinv2, M1_);

  // ---- layer 2 (X = fused pool of x1) -> x3 (bufB) + fused score2
  k_mm<64,64,1><<<dim3(M1_/64,1),256,0,stream>>>(bufA, W2, bufH, M1_, 32, 64,
      idx2, vals2, nullptr,nullptr,nullptr,0);
  k_gather_rm<64,true><<<NB(M1_*16),256,0,stream>>>(idx2, rowptr0, col0, rm02, dinv2, bufH, b2, bufB, M1_, p2, score);

  // ---- pool 2
  k_topk<<<B_,512,0,stream>>>(score, 512, K2_, idx4, vals4);
  k_compose_idx<<<NB(M2_),256,0,stream>>>(idx2, idx4, orig4, M2_);
  hipMemsetAsync(rm04, 0xFF, (size_t)M0_*4, stream);
  k_remap_set<<<NB(M2_),256,0,stream>>>(orig4, rm04, M2_);
  k_deg_orig<<<NB(M2_),256,0,stream>>>(orig4, rowptr0, col0, rm04, dinv4, M2_);

  // ---- layer 3 -> x5 (bufC) + fused score3
  k_mm<64,64,1><<<dim3(M2_/64,2),256,0,stream>>>(bufB, W3, bufH, M2_, 64, 128,
      idx4, vals4, nullptr,nullptr,nullptr,0);
  k_gather_rm<128,true><<<NB(M2_*32),256,0,stream>>>(orig4, rowptr0, col0, rm04, dinv4, bufH, b3, bufC, M2_, p3, score);

  // ---- pool 3
  k_topk<<<B_,256,0,stream>>>(score, 256, K3_, idx6, vals6);
  k_compose_idx<<<NB(M3_),256,0,stream>>>(orig4, idx6, orig6, M3_);
  hipMemsetAsync(rm06, 0xFF, (size_t)M0_*4, stream);
  k_remap_set<<<NB(M3_),256,0,stream>>>(orig6, rm06, M3_);
  k_deg_orig<<<NB(M3_),256,0,stream>>>(orig6, rowptr0, col0, rm06, dinv6, M3_);

  // ---- layer 4 -> x7 (bufD)
  k_mm<64,64,1><<<dim3(M3_/64,4),256,0,stream>>>(bufC, W4, bufH, M3_, 128, 256,
      idx6, vals6, nullptr,nullptr,nullptr,0);
  k_gather_rm<256,false><<<NB(M3_*64),256,0,stream>>>(orig6, rowptr0, col0, rm06, dinv6, bufH, b4, bufD, M3_, nullptr, nullptr);

  // ---- layer 5 (X = fused concat(x7 scattered, x5)) -> x9 (bufD)
  k_mm<64,64,2><<<dim3(M2_/64,2),256,0,stream>>>(bufC, W5, bufH, M2_, 384, 128,
      nullptr,nullptr, bufD, orig4, rm06, 64);
  k_gather_rm<128,false><<<NB(M2_*32),256,0,stream>>>(orig4, rowptr0, col0, rm04, dinv4, bufH, b5, bufD, M2_, nullptr, nullptr);

  // ---- layer 6 (X = fused concat(x9 scattered, x3)) -> x11 (bufC)
  k_mm<64,64,2><<<dim3(M1_/64,1),256,0,stream>>>(bufB, W6, bufH, M1_, 192, 64,
      nullptr,nullptr, bufD, idx2, rm04, 32);
  k_gather_rm<64,false><<<NB(M1_*16),256,0,stream>>>(idx2, rowptr0, col0, rm02, dinv2, bufH, b6, bufC, M1_, nullptr, nullptr);

  // ---- layer 7 (X = fused concat(x11 scattered, x1)) -> x13 (bufA)
  k_mm<128,32,2><<<dim3(M0_/128,1),256,0,stream>>>(bufA, W7, bufH, M0_, 96, 32,
      nullptr,nullptr, bufC, nullptr, rm02, 16);
  k_gather<32,false><<<NB(M0_*8),256,0,stream>>>(rowptr0, col0, dinv0, bufH, b7, bufA, M0_, nullptr, nullptr);

  // ---- head
  k_head<<<B_,256,0,stream>>>(bufA, Wl, Wc, bc, out);

  (void)in_sizes; (void)n_in; (void)out_size; (void)ws_size;
}

// Round 14
// 349.669 us; speedup vs baseline: 1.5443x; 1.1502x over previous
//
#include <hip/hip_runtime.h>
#include <hip/hip_bf16.h>
#include <math.h>

#define B_ 64
#define N_ 1024
#define E_ 524288
#define EPG_ 8192
#define K1_ 512
#define K2_ 256
#define K3_ 128
#define M0_ 65536
#define M1_ 32768
#define M2_ 16384
#define M3_ 8192

static __device__ __forceinline__ float eluf(float x){ return x > 0.f ? x : expm1f(x); }
static __device__ __forceinline__ float4 elu4(float4 v){
  float4 o; o.x=eluf(v.x); o.y=eluf(v.y); o.z=eluf(v.z); o.w=eluf(v.w); return o;
}

// Tiled GEMM (round-9 proven config — 6 in-kernel variants all tied; keep).
// MODE 0: H = X@W ; MODE 1: H = elu(X[perm[m]]*vals[m])@W ;
// MODE 2: H = elu(concat(Xd via rm/orig, Xskip))@W
template<int BM,int BN,int MODE>
__global__ __launch_bounds__(256) void k_mm(const float* __restrict__ X,
    const float* __restrict__ W, float* __restrict__ H, int M, int K, int N,
    const int* __restrict__ perm, const float* __restrict__ vals,
    const float* __restrict__ Xd, const int* __restrict__ orig,
    const int* __restrict__ rm, int WD4){
  constexpr int TX = BN/4;
  constexpr int TY = 256/TX;
  constexpr int RM = BM/TY;
  __shared__ float Xs[BM][36];
  __shared__ float Ws[32][BN];
  const int t = threadIdx.x;
  const int tx = t % TX, ty = t / TX;
  const int m0 = blockIdx.x*BM, n0 = blockIdx.y*BN;
  float acc[RM][4];
  #pragma unroll
  for (int r=0;r<RM;++r){acc[r][0]=0.f;acc[r][1]=0.f;acc[r][2]=0.f;acc[r][3]=0.f;}
  for (int k0=0;k0<K;k0+=32){
    #pragma unroll
    for (int l=0;l<BM/32;++l){
      int fi=l*256+t, row=fi>>3, q=fi&7;
      int m = m0+row;
      int c4 = (k0>>2)+q;
      float4 v;
      if (MODE==0){
        v = *(const float4*)(X + (size_t)m*K + (c4<<2));
      } else if (MODE==1){
        int pm = perm[m]; float vv = vals[m];
        float4 h = *(const float4*)(X + (size_t)pm*K + (c4<<2));
        v.x=eluf(h.x*vv); v.y=eluf(h.y*vv); v.z=eluf(h.z*vv); v.w=eluf(h.w*vv);
      } else {
        if (c4 < WD4){
          int o = orig ? orig[m] : m;
          int j = rm[o];
          if (j>=0) v = elu4(*(const float4*)(Xd + ((size_t)j*WD4 + c4)*4));
          else { v.x=0.f;v.y=0.f;v.z=0.f;v.w=0.f; }
        } else {
          int ws4 = (K>>2) - WD4;
          v = elu4(*(const float4*)(X + ((size_t)m*ws4 + (c4-WD4))*4));
        }
      }
      *(float4*)(&Xs[row][q*4]) = v;
    }
    #pragma unroll
    for (int l=0;l<BN/32;++l){
      int fi=l*256+t, wrow=fi/(BN/4), wq=fi%(BN/4);
      *(float4*)(&Ws[wrow][wq*4]) = *(const float4*)(W + (size_t)(k0+wrow)*N + n0 + wq*4);
    }
    __syncthreads();
    #pragma unroll
    for (int kq=0;kq<32;kq+=4){
      float4 xv[RM];
      #pragma unroll
      for (int r=0;r<RM;++r) xv[r] = *(const float4*)(&Xs[ty*RM+r][kq]);
      #pragma unroll
      for (int j=0;j<4;++j){
        float4 wv = *(const float4*)(&Ws[kq+j][tx*4]);
        #pragma unroll
        for (int r=0;r<RM;++r){
          float xs = (j==0)?xv[r].x:(j==1)?xv[r].y:(j==2)?xv[r].z:xv[r].w;
          acc[r][0]=fmaf(xs,wv.x,acc[r][0]);
          acc[r][1]=fmaf(xs,wv.y,acc[r][1]);
          acc[r][2]=fmaf(xs,wv.z,acc[r][2]);
          acc[r][3]=fmaf(xs,wv.w,acc[r][3]);
        }
      }
    }
    __syncthreads();
  }
  #pragma unroll
  for (int r=0;r<RM;++r){
    int m = m0 + ty*RM + r;
    float4 h; h.x=acc[r][0];h.y=acc[r][1];h.z=acc[r][2];h.w=acc[r][3];
    *(float4*)(H + (size_t)m*N + n0 + tx*4) = h;
  }
}

// ---- fused per-graph CSR build: deg (LDS atomics) + in-block scan + place.
// Graphs are disjoint and edge block g = [g*EPG,(g+1)*EPG), dst in g's range.
__global__ __launch_bounds__(1024) void k_csr(const int* __restrict__ src0,
    const int* __restrict__ dst0, int* __restrict__ rowptr,
    int* __restrict__ col, float* __restrict__ dinv){
  __shared__ int ldeg[1024];
  __shared__ int ps[1024];
  __shared__ int lcur[1024];
  const int g = blockIdx.x, t = threadIdx.x;
  const int ebase = g*EPG_, nbase = g<<10;
  ldeg[t] = 0;
  __syncthreads();
  #pragma unroll
  for (int i=0;i<EPG_/1024;++i){
    int e = ebase + i*1024 + t;
    atomicAdd(&ldeg[dst0[e] - nbase], 1);
  }
  __syncthreads();
  int d = ldeg[t];
  ps[t] = d; __syncthreads();
  for (int o=1;o<1024;o<<=1){
    int v = (t>=o) ? ps[t-o] : 0;
    __syncthreads(); ps[t] += v; __syncthreads();
  }
  int excl = ps[t] - d;
  rowptr[nbase + t] = ebase + excl;
  lcur[t] = excl;
  dinv[nbase + t] = rsqrtf((float)d + 2.f);
  if (g == B_-1 && t == 1023) rowptr[M0_] = E_;
  __syncthreads();
  #pragma unroll
  for (int i=0;i<EPG_/1024;++i){
    int e = ebase + i*1024 + t;
    int dl = dst0[e] - nbase;
    int p = atomicAdd(&lcur[dl], 1);
    col[ebase + p] = src0[e];
  }
}

// ---- fused per-graph pool: bitonic top-K + rm clear/scatter + orig compose
// + surviving-degree dinv. All lookups stay within the block's graph.
__global__ __launch_bounds__(1024) void k_pool(const float* __restrict__ score,
    int npg, int K, const int* __restrict__ prevOrig,
    const int* __restrict__ rowptr0, const int* __restrict__ col0,
    int* __restrict__ perm, float* __restrict__ vals,
    int* __restrict__ orig, int* __restrict__ rm, float* __restrict__ dinv){
  __shared__ float ss[1024]; __shared__ int si[1024];
  const int g = blockIdx.x, t = threadIdx.x;
  for (int i=t; i<1024; i+=npg) rm[(g<<10)+i] = -1;
  ss[t] = score[g*npg + t]; si[t] = t;
  __syncthreads();
  for (int k=2;k<=npg;k<<=1){
    for (int j=k>>1;j>0;j>>=1){
      int ixj = t ^ j;
      if (ixj > t){
        float s1=ss[t], s2=ss[ixj]; int i1=si[t], i2=si[ixj];
        bool aAfterB = (s1 < s2) || (s1==s2 && i1 > i2);
        bool sw = ((t & k)==0) ? aAfterB : !aAfterB;
        if (sw){ ss[t]=s2; si[t]=i2; ss[ixj]=s1; si[ixj]=i1; }
      }
      __syncthreads();
    }
  }
  int o = -1;
  if (t < K){
    int pl = g*npg + si[t];               // prev-level id
    perm[g*K+t] = pl;
    vals[g*K+t] = ss[t];
    o = prevOrig ? prevOrig[pl] : pl;     // level-0 id
    orig[g*K+t] = o;
    rm[o] = g*K + t;
  }
  __syncthreads();
  if (t < K){
    int beg = rowptr0[o], end = rowptr0[o+1];
    int d = 0;
    for (int j=beg;j<end;++j) d += (rm[col0[j]] >= 0) ? 1 : 0;
    dinv[g*K+t] = rsqrtf((float)d + 2.f);
  }
}

// ---- level-0 GCN aggregation; optional fused pool-score
template<int F, bool SCORE>
__global__ __launch_bounds__(256) void k_gather(const int* __restrict__ rowptr,
    const int* __restrict__ col, const float* __restrict__ dinv,
    const float* __restrict__ H, const float* __restrict__ bias,
    float* __restrict__ OUT, int M,
    const float* __restrict__ p, float* __restrict__ score){
  constexpr int FQ = F/4;
  int i = blockIdx.x*256+threadIdx.x;
  if (i >= M*FQ) return;
  int n = i/FQ, q = i - (i/FQ)*FQ;
  int beg = rowptr[n], end = rowptr[n+1];
  float4 acc; acc.x=0.f;acc.y=0.f;acc.z=0.f;acc.w=0.f;
  for (int j=beg;j<end;++j){
    int s = col[j];
    float c = dinv[s];
    float4 h = *(const float4*)(H + (size_t)s*F + q*4);
    acc.x=fmaf(c,h.x,acc.x); acc.y=fmaf(c,h.y,acc.y);
    acc.z=fmaf(c,h.z,acc.z); acc.w=fmaf(c,h.w,acc.w);
  }
  float dn = dinv[n];
  float sc = 2.f*dn*dn;
  float4 hn = *(const float4*)(H + (size_t)n*F + q*4);
  float4 bv = *(const float4*)(bias + q*4);
  float4 o;
  o.x = eluf(fmaf(sc,hn.x,fmaf(dn,acc.x,bv.x)));
  o.y = eluf(fmaf(sc,hn.y,fmaf(dn,acc.y,bv.y)));
  o.z = eluf(fmaf(sc,hn.z,fmaf(dn,acc.z,bv.z)));
  o.w = eluf(fmaf(sc,hn.w,fmaf(dn,acc.w,bv.w)));
  *(float4*)(OUT + (size_t)n*F + q*4) = o;
  if (SCORE){
    float4 pv = *(const float4*)(p + q*4);
    float dot = o.x*pv.x + o.y*pv.y + o.z*pv.z + o.w*pv.w;
    float n2  = pv.x*pv.x + pv.y*pv.y + pv.z*pv.z + pv.w*pv.w;
    #pragma unroll
    for (int mk=FQ>>1; mk>0; mk>>=1){
      dot += __shfl_xor(dot, mk);
      n2  += __shfl_xor(n2,  mk);
    }
    if (q==0) score[n] = tanhf(dot * rsqrtf(n2));
  }
}

// ---- pooled-level GCN aggregation through rm filter; optional fused score
template<int F, bool SCORE>
__global__ __launch_bounds__(256) void k_gather_rm(const int* __restrict__ orig,
    const int* __restrict__ rowptr0, const int* __restrict__ col0,
    const int* __restrict__ rm, const float* __restrict__ dinv,
    const float* __restrict__ H, const float* __restrict__ bias,
    float* __restrict__ OUT, int M,
    const float* __restrict__ p, float* __restrict__ score){
  constexpr int FQ = F/4;
  int i = blockIdx.x*256+threadIdx.x;
  if (i >= M*FQ) return;
  int n = i/FQ, q = i - (i/FQ)*FQ;
  int o = orig[n];
  int beg = rowptr0[o], end = rowptr0[o+1];
  float4 acc; acc.x=0.f;acc.y=0.f;acc.z=0.f;acc.w=0.f;
  for (int j=beg;j<end;++j){
    int s = rm[col0[j]];
    if (s >= 0){
      float c = dinv[s];
      float4 h = *(const float4*)(H + (size_t)s*F + q*4);
      acc.x=fmaf(c,h.x,acc.x); acc.y=fmaf(c,h.y,acc.y);
      acc.z=fmaf(c,h.z,acc.z); acc.w=fmaf(c,h.w,acc.w);
    }
  }
  float dn = dinv[n];
  float sc = 2.f*dn*dn;
  float4 hn = *(const float4*)(H + (size_t)n*F + q*4);
  float4 bv = *(const float4*)(bias + q*4);
  float4 ov;
  ov.x = eluf(fmaf(sc,hn.x,fmaf(dn,acc.x,bv.x)));
  ov.y = eluf(fmaf(sc,hn.y,fmaf(dn,acc.y,bv.y)));
  ov.z = eluf(fmaf(sc,hn.z,fmaf(dn,acc.z,bv.z)));
  ov.w = eluf(fmaf(sc,hn.w,fmaf(dn,acc.w,bv.w)));
  *(float4*)(OUT + (size_t)n*F + q*4) = ov;
  if (SCORE){
    float4 pv = *(const float4*)(p + q*4);
    float dot = ov.x*pv.x + ov.y*pv.y + ov.z*pv.z + ov.w*pv.w;
    float n2  = pv.x*pv.x + pv.y*pv.y + pv.z*pv.z + pv.w*pv.w;
    #pragma unroll
    for (int mk=FQ>>1; mk>0; mk>>=1){
      dot += __shfl_xor(dot, mk);
      n2  += __shfl_xor(n2,  mk);
    }
    if (q==0) score[n] = tanhf(dot * rsqrtf(n2));
  }
}

// per-graph global max/mean pool over (1024,32), then MLP head + log_softmax
__global__ void k_head(const float* __restrict__ x13, const float* __restrict__ Wl,
                       const float* __restrict__ Wc, const float* __restrict__ bc,
                       float* __restrict__ out){
  __shared__ float smax[256], ssum[256];
  __shared__ float gv[64], g2[64], logit[10];
  int g = blockIdx.x, t = threadIdx.x;
  int f = t & 31, r0 = t >> 5;
  float mx = -3.4e38f, sm = 0.f;
  const float* base = x13 + (size_t)g*N_*32;
  for (int r=r0; r<N_; r+=8){ float v = base[r*32+f]; mx = fmaxf(mx,v); sm += v; }
  smax[t]=mx; ssum[t]=sm; __syncthreads();
  if (t<128){ smax[t]=fmaxf(smax[t],smax[t+128]); ssum[t]+=ssum[t+128]; } __syncthreads();
  if (t<64){ smax[t]=fmaxf(smax[t],smax[t+64]); ssum[t]+=ssum[t+64]; } __syncthreads();
  if (t<32){
    float m2 = fmaxf(smax[t],smax[t+32]); float s2 = ssum[t]+ssum[t+32];
    gv[t] = eluf(m2); gv[32+t] = eluf(s2 * (1.f/N_));
  }
  __syncthreads();
  if (t<64){
    float acc=0.f;
    #pragma unroll
    for (int i2=0;i2<64;++i2) acc = fmaf(gv[i2], Wl[i2*64+t], acc);
    g2[t] = eluf(acc);
  }
  __syncthreads();
  if (t<10){
    float acc = bc[t];
    #pragma unroll
    for (int j=0;j<64;++j) acc = fmaf(g2[j], Wc[j*10+t], acc);
    logit[t] = acc;
  }
  __syncthreads();
  if (t==0){
    float m=-3.4e38f; for (int c=0;c<10;++c) m=fmaxf(m,logit[c]);
    float s=0.f; for (int c=0;c<10;++c) s += expf(logit[c]-m);
    float lse = m + logf(s);
    for (int c=0;c<10;++c) out[g*10+c] = logit[c]-lse;
  }
}

extern "C" void kernel_launch(void* const* d_in, const int* in_sizes, int n_in,
                              void* d_out, int out_size, void* d_ws, size_t ws_size,
                              hipStream_t stream){
  const float* x  = (const float*)d_in[0];
  const float* W1 = (const float*)d_in[1];
  const float* b1 = (const float*)d_in[2];
  const float* p1 = (const float*)d_in[3];
  const float* W2 = (const float*)d_in[4];
  const float* b2 = (const float*)d_in[5];
  const float* p2 = (const float*)d_in[6];
  const float* W3 = (const float*)d_in[7];
  const float* b3 = (const float*)d_in[8];
  const float* p3 = (const float*)d_in[9];
  const float* W4 = (const float*)d_in[10];
  const float* b4 = (const float*)d_in[11];
  const float* W5 = (const float*)d_in[12];
  const float* b5 = (const float*)d_in[13];
  const float* W6 = (const float*)d_in[14];
  const float* b6 = (const float*)d_in[15];
  const float* W7 = (const float*)d_in[16];
  const float* b7 = (const float*)d_in[17];
  const float* Wl = (const float*)d_in[18];
  const float* Wc = (const float*)d_in[19];
  const float* bc = (const float*)d_in[20];
  const int* src0 = (const int*)d_in[21];
  const int* dst0 = (const int*)d_in[22];
  float* out = (float*)d_out;

  char* wsp = (char*)d_ws;
  size_t off = 0;
  auto alloc = [&](size_t bytes)->char*{
    char* p = wsp + off;
    off += (bytes + 255) & ~(size_t)255;
    return p;
  };
  float* bufA = (float*)alloc((size_t)2097152*4);   // x1 / x13
  float* bufB = (float*)alloc((size_t)2097152*4);   // x3
  float* bufC = (float*)alloc((size_t)2097152*4);   // x5 / x11
  float* bufD = (float*)alloc((size_t)2097152*4);   // x7 / x9
  float* bufH = (float*)alloc((size_t)2097152*4);   // pre-norm H
  float* score= (float*)alloc((size_t)M0_*4);
  float* vals2= (float*)alloc((size_t)M1_*4);
  float* vals4= (float*)alloc((size_t)M2_*4);
  float* vals6= (float*)alloc((size_t)M3_*4);
  int* idx2 = (int*)alloc((size_t)M1_*4);   // level2 -> level0 (perm AND orig)
  int* idx4 = (int*)alloc((size_t)M2_*4);   // level4 -> level2 (perm)
  int* idx6 = (int*)alloc((size_t)M3_*4);   // level6 -> level4 (perm)
  int* orig4 = (int*)alloc((size_t)M2_*4);  // level4 -> level0
  int* orig6 = (int*)alloc((size_t)M3_*4);  // level6 -> level0
  int* rm02 = (int*)alloc((size_t)M0_*4);
  int* rm04 = (int*)alloc((size_t)M0_*4);
  int* rm06 = (int*)alloc((size_t)M0_*4);
  int* col0 = (int*)alloc((size_t)E_*4);
  int* rowptr0 = (int*)alloc((size_t)(M0_+1)*4);
  float* dinv0 = (float*)alloc((size_t)M0_*4);
  float* dinv2 = (float*)alloc((size_t)M1_*4);
  float* dinv4 = (float*)alloc((size_t)M2_*4);
  float* dinv6 = (float*)alloc((size_t)M3_*4);

  auto NB = [](int total){ return (total+255)/256; };

  // ---- level-0 CSR: ONE fused per-graph kernel (was 6 dispatches)
  k_csr<<<B_,1024,0,stream>>>(src0, dst0, rowptr0, col0, dinv0);

  // ---- layer 1: H1 = x@W1; x1 = gather (bufA) + fused score1
  k_mm<128,32,0><<<dim3(M0_/128,1),256,0,stream>>>(x, W1, bufH, M0_, 128, 32,
      nullptr,nullptr,nullptr,nullptr,nullptr,0);
  k_gather<32,true><<<NB(M0_*8),256,0,stream>>>(rowptr0, col0, dinv0, bufH, b1, bufA, M0_, p1, score);

  // ---- pool 1: ONE fused per-graph kernel (was 5 dispatches)
  k_pool<<<B_,1024,0,stream>>>(score, 1024, K1_, nullptr, rowptr0, col0,
      idx2, vals2, idx2, rm02, dinv2);

  // ---- layer 2 (fused pool staging) -> x3 (bufB) + score2
  k_mm<64,64,1><<<dim3(M1_/64,1),256,0,stream>>>(bufA, W2, bufH, M1_, 32, 64,
      idx2, vals2, nullptr,nullptr,nullptr,0);
  k_gather_rm<64,true><<<NB(M1_*16),256,0,stream>>>(idx2, rowptr0, col0, rm02, dinv2, bufH, b2, bufB, M1_, p2, score);

  // ---- pool 2
  k_pool<<<B_,512,0,stream>>>(score, 512, K2_, idx2, rowptr0, col0,
      idx4, vals4, orig4, rm04, dinv4);

  // ---- layer 3 -> x5 (bufC) + score3
  k_mm<64,64,1><<<dim3(M2_/64,2),256,0,stream>>>(bufB, W3, bufH, M2_, 64, 128,
      idx4, vals4, nullptr,nullptr,nullptr,0);
  k_gather_rm<128,true><<<NB(M2_*32),256,0,stream>>>(orig4, rowptr0, col0, rm04, dinv4, bufH, b3, bufC, M2_, p3, score);

  // ---- pool 3
  k_pool<<<B_,256,0,stream>>>(score, 256, K3_, orig4, rowptr0, col0,
      idx6, vals6, orig6, rm06, dinv6);

  // ---- layer 4 -> x7 (bufD)
  k_mm<64,64,1><<<dim3(M3_/64,4),256,0,stream>>>(bufC, W4, bufH, M3_, 128, 256,
      idx6, vals6, nullptr,nullptr,nullptr,0);
  k_gather_rm<256,false><<<NB(M3_*64),256,0,stream>>>(orig6, rowptr0, col0, rm06, dinv6, bufH, b4, bufD, M3_, nullptr, nullptr);

  // ---- layer 5 (fused concat staging) -> x9 (bufD)
  k_mm<64,64,2><<<dim3(M2_/64,2),256,0,stream>>>(bufC, W5, bufH, M2_, 384, 128,
      nullptr,nullptr, bufD, orig4, rm06, 64);
  k_gather_rm<128,false><<<NB(M2_*32),256,0,stream>>>(orig4, rowptr0, col0, rm04, dinv4, bufH, b5, bufD, M2_, nullptr, nullptr);

  // ---- layer 6 -> x11 (bufC)
  k_mm<64,64,2><<<dim3(M1_/64,1),256,0,stream>>>(bufB, W6, bufH, M1_, 192, 64,
      nullptr,nullptr, bufD, idx2, rm04, 32);
  k_gather_rm<64,false><<<NB(M1_*16),256,0,stream>>>(idx2, rowptr0, col0, rm02, dinv2, bufH, b6, bufC, M1_, nullptr, nullptr);

  // ---- layer 7 -> x13 (bufA)
  k_mm<128,32,2><<<dim3(M0_/128,1),256,0,stream>>>(bufA, W7, bufH, M0_, 96, 32,
      nullptr,nullptr, bufC, nullptr, rm02, 16);
  k_gather<32,false><<<NB(M0_*8),256,0,stream>>>(rowptr0, col0, dinv0, bufH, b7, bufA, M0_, nullptr, nullptr);

  // ---- head
  k_head<<<B_,256,0,stream>>>(bufA, Wl, Wc, bc, out);

  (void)in_sizes; (void)n_in; (void)out_size; (void)ws_size;
}

// Round 15
// 336.292 us; speedup vs baseline: 1.6057x; 1.0398x over previous
//
#include <hip/hip_runtime.h>
#include <hip/hip_bf16.h>
#include <math.h>

#define B_ 64
#define N_ 1024
#define E_ 524288
#define EPG_ 8192
#define K1_ 512
#define K2_ 256
#define K3_ 128
#define M0_ 65536
#define M1_ 32768
#define M2_ 16384
#define M3_ 8192

static __device__ __forceinline__ float eluf(float x){ return x > 0.f ? x : expm1f(x); }
static __device__ __forceinline__ float4 elu4(float4 v){
  float4 o; o.x=eluf(v.x); o.y=eluf(v.y); o.z=eluf(v.z); o.w=eluf(v.w); return o;
}
// bf16 round-to-nearest-even pack/unpack (H tensor only; all math stays fp32)
static __device__ __forceinline__ unsigned short f2bf(float f){
  union{float f; unsigned u;} v; v.f=f;
  unsigned u = v.u + 0x7FFF + ((v.u>>16)&1);
  return (unsigned short)(u>>16);
}
static __device__ __forceinline__ float bf2f(unsigned short h){
  union{unsigned u; float f;} v; v.u = ((unsigned)h)<<16;
  return v.f;
}
static __device__ __forceinline__ float4 ldH4(const unsigned short* __restrict__ H, size_t idx){
  ushort4 r = *(const ushort4*)(H + idx);
  float4 o; o.x=bf2f(r.x); o.y=bf2f(r.y); o.z=bf2f(r.z); o.w=bf2f(r.w);
  return o;
}

// Tiled GEMM (round-9 proven config). H output stored as bf16 (halves the
// mm->gather dispatch-boundary traffic — the measured cost driver).
// MODE 0: H = X@W ; MODE 1: H = elu(X[perm[m]]*vals[m])@W ;
// MODE 2: H = elu(concat(Xd via rm/orig, Xskip))@W
template<int BM,int BN,int MODE>
__global__ __launch_bounds__(256) void k_mm(const float* __restrict__ X,
    const float* __restrict__ W, unsigned short* __restrict__ H, int M, int K, int N,
    const int* __restrict__ perm, const float* __restrict__ vals,
    const float* __restrict__ Xd, const int* __restrict__ orig,
    const int* __restrict__ rm, int WD4){
  constexpr int TX = BN/4;
  constexpr int TY = 256/TX;
  constexpr int RM = BM/TY;
  __shared__ float Xs[BM][36];
  __shared__ float Ws[32][BN];
  const int t = threadIdx.x;
  const int tx = t % TX, ty = t / TX;
  const int m0 = blockIdx.x*BM, n0 = blockIdx.y*BN;
  float acc[RM][4];
  #pragma unroll
  for (int r=0;r<RM;++r){acc[r][0]=0.f;acc[r][1]=0.f;acc[r][2]=0.f;acc[r][3]=0.f;}
  for (int k0=0;k0<K;k0+=32){
    #pragma unroll
    for (int l=0;l<BM/32;++l){
      int fi=l*256+t, row=fi>>3, q=fi&7;
      int m = m0+row;
      int c4 = (k0>>2)+q;
      float4 v;
      if (MODE==0){
        v = *(const float4*)(X + (size_t)m*K + (c4<<2));
      } else if (MODE==1){
        int pm = perm[m]; float vv = vals[m];
        float4 h = *(const float4*)(X + (size_t)pm*K + (c4<<2));
        v.x=eluf(h.x*vv); v.y=eluf(h.y*vv); v.z=eluf(h.z*vv); v.w=eluf(h.w*vv);
      } else {
        if (c4 < WD4){
          int o = orig ? orig[m] : m;
          int j = rm[o];
          if (j>=0) v = elu4(*(const float4*)(Xd + ((size_t)j*WD4 + c4)*4));
          else { v.x=0.f;v.y=0.f;v.z=0.f;v.w=0.f; }
        } else {
          int ws4 = (K>>2) - WD4;
          v = elu4(*(const float4*)(X + ((size_t)m*ws4 + (c4-WD4))*4));
        }
      }
      *(float4*)(&Xs[row][q*4]) = v;
    }
    #pragma unroll
    for (int l=0;l<BN/32;++l){
      int fi=l*256+t, wrow=fi/(BN/4), wq=fi%(BN/4);
      *(float4*)(&Ws[wrow][wq*4]) = *(const float4*)(W + (size_t)(k0+wrow)*N + n0 + wq*4);
    }
    __syncthreads();
    #pragma unroll
    for (int kq=0;kq<32;kq+=4){
      float4 xv[RM];
      #pragma unroll
      for (int r=0;r<RM;++r) xv[r] = *(const float4*)(&Xs[ty*RM+r][kq]);
      #pragma unroll
      for (int j=0;j<4;++j){
        float4 wv = *(const float4*)(&Ws[kq+j][tx*4]);
        #pragma unroll
        for (int r=0;r<RM;++r){
          float xs = (j==0)?xv[r].x:(j==1)?xv[r].y:(j==2)?xv[r].z:xv[r].w;
          acc[r][0]=fmaf(xs,wv.x,acc[r][0]);
          acc[r][1]=fmaf(xs,wv.y,acc[r][1]);
          acc[r][2]=fmaf(xs,wv.z,acc[r][2]);
          acc[r][3]=fmaf(xs,wv.w,acc[r][3]);
        }
      }
    }
    __syncthreads();
  }
  #pragma unroll
  for (int r=0;r<RM;++r){
    int m = m0 + ty*RM + r;
    ushort4 h;
    h.x=f2bf(acc[r][0]); h.y=f2bf(acc[r][1]); h.z=f2bf(acc[r][2]); h.w=f2bf(acc[r][3]);
    *(ushort4*)(H + (size_t)m*N + n0 + tx*4) = h;
  }
}

// ---- fused per-graph CSR build (round-14 WIN kernel, unchanged)
__global__ __launch_bounds__(1024) void k_csr(const int* __restrict__ src0,
    const int* __restrict__ dst0, int* __restrict__ rowptr,
    int* __restrict__ col, float* __restrict__ dinv){
  __shared__ int ldeg[1024];
  __shared__ int ps[1024];
  __shared__ int lcur[1024];
  const int g = blockIdx.x, t = threadIdx.x;
  const int ebase = g*EPG_, nbase = g<<10;
  ldeg[t] = 0;
  __syncthreads();
  #pragma unroll
  for (int i=0;i<EPG_/1024;++i){
    int e = ebase + i*1024 + t;
    atomicAdd(&ldeg[dst0[e] - nbase], 1);
  }
  __syncthreads();
  int d = ldeg[t];
  ps[t] = d; __syncthreads();
  for (int o=1;o<1024;o<<=1){
    int v = (t>=o) ? ps[t-o] : 0;
    __syncthreads(); ps[t] += v; __syncthreads();
  }
  int excl = ps[t] - d;
  rowptr[nbase + t] = ebase + excl;
  lcur[t] = excl;
  dinv[nbase + t] = rsqrtf((float)d + 2.f);
  if (g == B_-1 && t == 1023) rowptr[M0_] = E_;
  __syncthreads();
  #pragma unroll
  for (int i=0;i<EPG_/1024;++i){
    int e = ebase + i*1024 + t;
    int dl = dst0[e] - nbase;
    int p = atomicAdd(&lcur[dl], 1);
    col[ebase + p] = src0[e];
  }
}

// ---- fused per-graph pool (round-14 WIN kernel, unchanged)
__global__ __launch_bounds__(1024) void k_pool(const float* __restrict__ score,
    int npg, int K, const int* __restrict__ prevOrig,
    const int* __restrict__ rowptr0, const int* __restrict__ col0,
    int* __restrict__ perm, float* __restrict__ vals,
    int* __restrict__ orig, int* __restrict__ rm, float* __restrict__ dinv){
  __shared__ float ss[1024]; __shared__ int si[1024];
  const int g = blockIdx.x, t = threadIdx.x;
  for (int i=t; i<1024; i+=npg) rm[(g<<10)+i] = -1;
  ss[t] = score[g*npg + t]; si[t] = t;
  __syncthreads();
  for (int k=2;k<=npg;k<<=1){
    for (int j=k>>1;j>0;j>>=1){
      int ixj = t ^ j;
      if (ixj > t){
        float s1=ss[t], s2=ss[ixj]; int i1=si[t], i2=si[ixj];
        bool aAfterB = (s1 < s2) || (s1==s2 && i1 > i2);
        bool sw = ((t & k)==0) ? aAfterB : !aAfterB;
        if (sw){ ss[t]=s2; si[t]=i2; ss[ixj]=s1; si[ixj]=i1; }
      }
      __syncthreads();
    }
  }
  int o = -1;
  if (t < K){
    int pl = g*npg + si[t];
    perm[g*K+t] = pl;
    vals[g*K+t] = ss[t];
    o = prevOrig ? prevOrig[pl] : pl;
    orig[g*K+t] = o;
    rm[o] = g*K + t;
  }
  __syncthreads();
  if (t < K){
    int beg = rowptr0[o], end = rowptr0[o+1];
    int d = 0;
    for (int j=beg;j<end;++j) d += (rm[col0[j]] >= 0) ? 1 : 0;
    dinv[g*K+t] = rsqrtf((float)d + 2.f);
  }
}

// ---- level-0 GCN aggregation (H in bf16); optional fused pool-score
template<int F, bool SCORE>
__global__ __launch_bounds__(256) void k_gather(const int* __restrict__ rowptr,
    const int* __restrict__ col, const float* __restrict__ dinv,
    const unsigned short* __restrict__ H, const float* __restrict__ bias,
    float* __restrict__ OUT, int M,
    const float* __restrict__ p, float* __restrict__ score){
  constexpr int FQ = F/4;
  int i = blockIdx.x*256+threadIdx.x;
  if (i >= M*FQ) return;
  int n = i/FQ, q = i - (i/FQ)*FQ;
  int beg = rowptr[n], end = rowptr[n+1];
  float4 acc; acc.x=0.f;acc.y=0.f;acc.z=0.f;acc.w=0.f;
  for (int j=beg;j<end;++j){
    int s = col[j];
    float c = dinv[s];
    float4 h = ldH4(H, (size_t)s*F + q*4);
    acc.x=fmaf(c,h.x,acc.x); acc.y=fmaf(c,h.y,acc.y);
    acc.z=fmaf(c,h.z,acc.z); acc.w=fmaf(c,h.w,acc.w);
  }
  float dn = dinv[n];
  float sc = 2.f*dn*dn;
  float4 hn = ldH4(H, (size_t)n*F + q*4);
  float4 bv = *(const float4*)(bias + q*4);
  float4 o;
  o.x = eluf(fmaf(sc,hn.x,fmaf(dn,acc.x,bv.x)));
  o.y = eluf(fmaf(sc,hn.y,fmaf(dn,acc.y,bv.y)));
  o.z = eluf(fmaf(sc,hn.z,fmaf(dn,acc.z,bv.z)));
  o.w = eluf(fmaf(sc,hn.w,fmaf(dn,acc.w,bv.w)));
  *(float4*)(OUT + (size_t)n*F + q*4) = o;
  if (SCORE){
    float4 pv = *(const float4*)(p + q*4);
    float dot = o.x*pv.x + o.y*pv.y + o.z*pv.z + o.w*pv.w;
    float n2  = pv.x*pv.x + pv.y*pv.y + pv.z*pv.z + pv.w*pv.w;
    #pragma unroll
    for (int mk=FQ>>1; mk>0; mk>>=1){
      dot += __shfl_xor(dot, mk);
      n2  += __shfl_xor(n2,  mk);
    }
    if (q==0) score[n] = tanhf(dot * rsqrtf(n2));
  }
}

// ---- pooled-level GCN aggregation through rm filter (H in bf16)
template<int F, bool SCORE>
__global__ __launch_bounds__(256) void k_gather_rm(const int* __restrict__ orig,
    const int* __restrict__ rowptr0, const int* __restrict__ col0,
    const int* __restrict__ rm, const float* __restrict__ dinv,
    const unsigned short* __restrict__ H, const float* __restrict__ bias,
    float* __restrict__ OUT, int M,
    const float* __restrict__ p, float* __restrict__ score){
  constexpr int FQ = F/4;
  int i = blockIdx.x*256+threadIdx.x;
  if (i >= M*FQ) return;
  int n = i/FQ, q = i - (i/FQ)*FQ;
  int o = orig[n];
  int beg = rowptr0[o], end = rowptr0[o+1];
  float4 acc; acc.x=0.f;acc.y=0.f;acc.z=0.f;acc.w=0.f;
  for (int j=beg;j<end;++j){
    int s = rm[col0[j]];
    if (s >= 0){
      float c = dinv[s];
      float4 h = ldH4(H, (size_t)s*F + q*4);
      acc.x=fmaf(c,h.x,acc.x); acc.y=fmaf(c,h.y,acc.y);
      acc.z=fmaf(c,h.z,acc.z); acc.w=fmaf(c,h.w,acc.w);
    }
  }
  float dn = dinv[n];
  float sc = 2.f*dn*dn;
  float4 hn = ldH4(H, (size_t)n*F + q*4);
  float4 bv = *(const float4*)(bias + q*4);
  float4 ov;
  ov.x = eluf(fmaf(sc,hn.x,fmaf(dn,acc.x,bv.x)));
  ov.y = eluf(fmaf(sc,hn.y,fmaf(dn,acc.y,bv.y)));
  ov.z = eluf(fmaf(sc,hn.z,fmaf(dn,acc.z,bv.z)));
  ov.w = eluf(fmaf(sc,hn.w,fmaf(dn,acc.w,bv.w)));
  *(float4*)(OUT + (size_t)n*F + q*4) = ov;
  if (SCORE){
    float4 pv = *(const float4*)(p + q*4);
    float dot = ov.x*pv.x + ov.y*pv.y + ov.z*pv.z + ov.w*pv.w;
    float n2  = pv.x*pv.x + pv.y*pv.y + pv.z*pv.z + pv.w*pv.w;
    #pragma unroll
    for (int mk=FQ>>1; mk>0; mk>>=1){
      dot += __shfl_xor(dot, mk);
      n2  += __shfl_xor(n2,  mk);
    }
    if (q==0) score[n] = tanhf(dot * rsqrtf(n2));
  }
}

// per-graph global max/mean pool over (1024,32), then MLP head + log_softmax
__global__ void k_head(const float* __restrict__ x13, const float* __restrict__ Wl,
                       const float* __restrict__ Wc, const float* __restrict__ bc,
                       float* __restrict__ out){
  __shared__ float smax[256], ssum[256];
  __shared__ float gv[64], g2[64], logit[10];
  int g = blockIdx.x, t = threadIdx.x;
  int f = t & 31, r0 = t >> 5;
  float mx = -3.4e38f, sm = 0.f;
  const float* base = x13 + (size_t)g*N_*32;
  for (int r=r0; r<N_; r+=8){ float v = base[r*32+f]; mx = fmaxf(mx,v); sm += v; }
  smax[t]=mx; ssum[t]=sm; __syncthreads();
  if (t<128){ smax[t]=fmaxf(smax[t],smax[t+128]); ssum[t]+=ssum[t+128]; } __syncthreads();
  if (t<64){ smax[t]=fmaxf(smax[t],smax[t+64]); ssum[t]+=ssum[t+64]; } __syncthreads();
  if (t<32){
    float m2 = fmaxf(smax[t],smax[t+32]); float s2 = ssum[t]+ssum[t+32];
    gv[t] = eluf(m2); gv[32+t] = eluf(s2 * (1.f/N_));
  }
  __syncthreads();
  if (t<64){
    float acc=0.f;
    #pragma unroll
    for (int i2=0;i2<64;++i2) acc = fmaf(gv[i2], Wl[i2*64+t], acc);
    g2[t] = eluf(acc);
  }
  __syncthreads();
  if (t<10){
    float acc = bc[t];
    #pragma unroll
    for (int j=0;j<64;++j) acc = fmaf(g2[j], Wc[j*10+t], acc);
    logit[t] = acc;
  }
  __syncthreads();
  if (t==0){
    float m=-3.4e38f; for (int c=0;c<10;++c) m=fmaxf(m,logit[c]);
    float s=0.f; for (int c=0;c<10;++c) s += expf(logit[c]-m);
    float lse = m + logf(s);
    for (int c=0;c<10;++c) out[g*10+c] = logit[c]-lse;
  }
}

extern "C" void kernel_launch(void* const* d_in, const int* in_sizes, int n_in,
                              void* d_out, int out_size, void* d_ws, size_t ws_size,
                              hipStream_t stream){
  const float* x  = (const float*)d_in[0];
  const float* W1 = (const float*)d_in[1];
  const float* b1 = (const float*)d_in[2];
  const float* p1 = (const float*)d_in[3];
  const float* W2 = (const float*)d_in[4];
  const float* b2 = (const float*)d_in[5];
  const float* p2 = (const float*)d_in[6];
  const float* W3 = (const float*)d_in[7];
  const float* b3 = (const float*)d_in[8];
  const float* p3 = (const float*)d_in[9];
  const float* W4 = (const float*)d_in[10];
  const float* b4 = (const float*)d_in[11];
  const float* W5 = (const float*)d_in[12];
  const float* b5 = (const float*)d_in[13];
  const float* W6 = (const float*)d_in[14];
  const float* b6 = (const float*)d_in[15];
  const float* W7 = (const float*)d_in[16];
  const float* b7 = (const float*)d_in[17];
  const float* Wl = (const float*)d_in[18];
  const float* Wc = (const float*)d_in[19];
  const float* bc = (const float*)d_in[20];
  const int* src0 = (const int*)d_in[21];
  const int* dst0 = (const int*)d_in[22];
  float* out = (float*)d_out;

  char* wsp = (char*)d_ws;
  size_t off = 0;
  auto alloc = [&](size_t bytes)->char*{
    char* p = wsp + off;
    off += (bytes + 255) & ~(size_t)255;
    return p;
  };
  float* bufA = (float*)alloc((size_t)2097152*4);   // x1 / x13
  float* bufB = (float*)alloc((size_t)2097152*4);   // x3
  float* bufC = (float*)alloc((size_t)2097152*4);   // x5 / x11
  float* bufD = (float*)alloc((size_t)2097152*4);   // x7 / x9
  unsigned short* bufH = (unsigned short*)alloc((size_t)2097152*2);  // bf16 H
  float* score= (float*)alloc((size_t)M0_*4);
  float* vals2= (float*)alloc((size_t)M1_*4);
  float* vals4= (float*)alloc((size_t)M2_*4);
  float* vals6= (float*)alloc((size_t)M3_*4);
  int* idx2 = (int*)alloc((size_t)M1_*4);   // level2 -> level0 (perm AND orig)
  int* idx4 = (int*)alloc((size_t)M2_*4);   // level4 -> level2 (perm)
  int* idx6 = (int*)alloc((size_t)M3_*4);   // level6 -> level4 (perm)
  int* orig4 = (int*)alloc((size_t)M2_*4);  // level4 -> level0
  int* orig6 = (int*)alloc((size_t)M3_*4);  // level6 -> level0
  int* rm02 = (int*)alloc((size_t)M0_*4);
  int* rm04 = (int*)alloc((size_t)M0_*4);
  int* rm06 = (int*)alloc((size_t)M0_*4);
  int* col0 = (int*)alloc((size_t)E_*4);
  int* rowptr0 = (int*)alloc((size_t)(M0_+1)*4);
  float* dinv0 = (float*)alloc((size_t)M0_*4);
  float* dinv2 = (float*)alloc((size_t)M1_*4);
  float* dinv4 = (float*)alloc((size_t)M2_*4);
  float* dinv6 = (float*)alloc((size_t)M3_*4);

  auto NB = [](int total){ return (total+255)/256; };

  // ---- level-0 CSR: ONE fused per-graph kernel
  k_csr<<<B_,1024,0,stream>>>(src0, dst0, rowptr0, col0, dinv0);

  // ---- layer 1: H1 = x@W1; x1 = gather (bufA) + fused score1
  k_mm<128,32,0><<<dim3(M0_/128,1),256,0,stream>>>(x, W1, bufH, M0_, 128, 32,
      nullptr,nullptr,nullptr,nullptr,nullptr,0);
  k_gather<32,true><<<NB(M0_*8),256,0,stream>>>(rowptr0, col0, dinv0, bufH, b1, bufA, M0_, p1, score);

  // ---- pool 1: ONE fused per-graph kernel
  k_pool<<<B_,1024,0,stream>>>(score, 1024, K1_, nullptr, rowptr0, col0,
      idx2, vals2, idx2, rm02, dinv2);

  // ---- layer 2 (fused pool staging) -> x3 (bufB) + score2
  k_mm<64,64,1><<<dim3(M1_/64,1),256,0,stream>>>(bufA, W2, bufH, M1_, 32, 64,
      idx2, vals2, nullptr,nullptr,nullptr,0);
  k_gather_rm<64,true><<<NB(M1_*16),256,0,stream>>>(idx2, rowptr0, col0, rm02, dinv2, bufH, b2, bufB, M1_, p2, score);

  // ---- pool 2
  k_pool<<<B_,512,0,stream>>>(score, 512, K2_, idx2, rowptr0, col0,
      idx4, vals4, orig4, rm04, dinv4);

  // ---- layer 3 -> x5 (bufC) + score3
  k_mm<64,64,1><<<dim3(M2_/64,2),256,0,stream>>>(bufB, W3, bufH, M2_, 64, 128,
      idx4, vals4, nullptr,nullptr,nullptr,0);
  k_gather_rm<128,true><<<NB(M2_*32),256,0,stream>>>(orig4, rowptr0, col0, rm04, dinv4, bufH, b3, bufC, M2_, p3, score);

  // ---- pool 3
  k_pool<<<B_,256,0,stream>>>(score, 256, K3_, orig4, rowptr0, col0,
      idx6, vals6, orig6, rm06, dinv6);

  // ---- layer 4 -> x7 (bufD)
  k_mm<64,64,1><<<dim3(M3_/64,4),256,0,stream>>>(bufC, W4, bufH, M3_, 128, 256,
      idx6, vals6, nullptr,nullptr,nullptr,0);
  k_gather_rm<256,false><<<NB(M3_*64),256,0,stream>>>(orig6, rowptr0, col0, rm06, dinv6, bufH, b4, bufD, M3_, nullptr, nullptr);

  // ---- layer 5 (fused concat staging) -> x9 (bufD)
  k_mm<64,64,2><<<dim3(M2_/64,2),256,0,stream>>>(bufC, W5, bufH, M2_, 384, 128,
      nullptr,nullptr, bufD, orig4, rm06, 64);
  k_gather_rm<128,false><<<NB(M2_*32),256,0,stream>>>(orig4, rowptr0, col0, rm04, dinv4, bufH, b5, bufD, M2_, nullptr, nullptr);

  // ---- layer 6 -> x11 (bufC)
  k_mm<64,64,2><<<dim3(M1_/64,1),256,0,stream>>>(bufB, W6, bufH, M1_, 192, 64,
      nullptr,nullptr, bufD, idx2, rm04, 32);
  k_gather_rm<64,false><<<NB(M1_*16),256,0,stream>>>(idx2, rowptr0, col0, rm02, dinv2, bufH, b6, bufC, M1_, nullptr, nullptr);

  // ---- layer 7 -> x13 (bufA)
  k_mm<128,32,2><<<dim3(M0_/128,1),256,0,stream>>>(bufA, W7, bufH, M0_, 96, 32,
      nullptr,nullptr, bufC, nullptr, rm02, 16);
  k_gather<32,false><<<NB(M0_*8),256,0,stream>>>(rowptr0, col0, dinv0, bufH, b7, bufA, M0_, nullptr, nullptr);

  // ---- head
  k_head<<<B_,256,0,stream>>>(bufA, Wl, Wc, bc, out);

  (void)in_sizes; (void)n_in; (void)out_size; (void)ws_size;
}

// Round 16
// 327.867 us; speedup vs baseline: 1.6470x; 1.0257x over previous
//
#include <hip/hip_runtime.h>
#include <hip/hip_bf16.h>
#include <math.h>

#define B_ 64
#define N_ 1024
#define E_ 524288
#define EPG_ 8192
#define K1_ 512
#define K2_ 256
#define K3_ 128
#define M0_ 65536
#define M1_ 32768
#define M2_ 16384
#define M3_ 8192

static __device__ __forceinline__ float eluf(float x){ return x > 0.f ? x : expm1f(x); }
// bf16 round-to-nearest-even pack/unpack. All math fp32; only storage is bf16.
static __device__ __forceinline__ unsigned short f2bf(float f){
  union{float f; unsigned u;} v; v.f=f;
  unsigned u = v.u + 0x7FFF + ((v.u>>16)&1);
  return (unsigned short)(u>>16);
}
static __device__ __forceinline__ float bf2f(unsigned short h){
  union{unsigned u; float f;} v; v.u = ((unsigned)h)<<16;
  return v.f;
}
static __device__ __forceinline__ float4 ldU4(const unsigned short* __restrict__ p, size_t idx){
  ushort4 r = *(const ushort4*)(p + idx);
  float4 o; o.x=bf2f(r.x); o.y=bf2f(r.y); o.z=bf2f(r.z); o.w=bf2f(r.w);
  return o;
}
static __device__ __forceinline__ void stU4(unsigned short* __restrict__ p, size_t idx, float4 v){
  ushort4 h; h.x=f2bf(v.x); h.y=f2bf(v.y); h.z=f2bf(v.z); h.w=f2bf(v.w);
  *(ushort4*)(p + idx) = h;
}

// Tiled GEMM (round-9 proven schedule). H output bf16; feature inputs bf16
// for MODE1/2 (MODE0 reads the external fp32 x).
// MODE 0: H = Xf@W ; MODE 1: H = elu(Xh[perm[m]]*vals[m])@W ;
// MODE 2: H = elu(concat(Xd via rm/orig, Xh))@W
template<int BM,int BN,int MODE>
__global__ __launch_bounds__(256) void k_mm(const float* __restrict__ Xf,
    const unsigned short* __restrict__ Xh,
    const float* __restrict__ W, unsigned short* __restrict__ H, int M, int K, int N,
    const int* __restrict__ perm, const float* __restrict__ vals,
    const unsigned short* __restrict__ Xd, const int* __restrict__ orig,
    const int* __restrict__ rm, int WD4){
  constexpr int TX = BN/4;
  constexpr int TY = 256/TX;
  constexpr int RM = BM/TY;
  __shared__ float Xs[BM][36];
  __shared__ float Ws[32][BN];
  const int t = threadIdx.x;
  const int tx = t % TX, ty = t / TX;
  const int m0 = blockIdx.x*BM, n0 = blockIdx.y*BN;
  float acc[RM][4];
  #pragma unroll
  for (int r=0;r<RM;++r){acc[r][0]=0.f;acc[r][1]=0.f;acc[r][2]=0.f;acc[r][3]=0.f;}
  for (int k0=0;k0<K;k0+=32){
    #pragma unroll
    for (int l=0;l<BM/32;++l){
      int fi=l*256+t, row=fi>>3, q=fi&7;
      int m = m0+row;
      int c4 = (k0>>2)+q;
      float4 v;
      if (MODE==0){
        v = *(const float4*)(Xf + (size_t)m*K + (c4<<2));
      } else if (MODE==1){
        int pm = perm[m]; float vv = vals[m];
        float4 h = ldU4(Xh, (size_t)pm*K + (c4<<2));
        v.x=eluf(h.x*vv); v.y=eluf(h.y*vv); v.z=eluf(h.z*vv); v.w=eluf(h.w*vv);
      } else {
        if (c4 < WD4){
          int o = orig ? orig[m] : m;
          int j = rm[o];
          if (j>=0){
            float4 h = ldU4(Xd, ((size_t)j*WD4 + c4)*4);
            v.x=eluf(h.x); v.y=eluf(h.y); v.z=eluf(h.z); v.w=eluf(h.w);
          } else { v.x=0.f;v.y=0.f;v.z=0.f;v.w=0.f; }
        } else {
          int ws4 = (K>>2) - WD4;
          float4 h = ldU4(Xh, ((size_t)m*ws4 + (c4-WD4))*4);
          v.x=eluf(h.x); v.y=eluf(h.y); v.z=eluf(h.z); v.w=eluf(h.w);
        }
      }
      *(float4*)(&Xs[row][q*4]) = v;
    }
    #pragma unroll
    for (int l=0;l<BN/32;++l){
      int fi=l*256+t, wrow=fi/(BN/4), wq=fi%(BN/4);
      *(float4*)(&Ws[wrow][wq*4]) = *(const float4*)(W + (size_t)(k0+wrow)*N + n0 + wq*4);
    }
    __syncthreads();
    #pragma unroll
    for (int kq=0;kq<32;kq+=4){
      float4 xv[RM];
      #pragma unroll
      for (int r=0;r<RM;++r) xv[r] = *(const float4*)(&Xs[ty*RM+r][kq]);
      #pragma unroll
      for (int j=0;j<4;++j){
        float4 wv = *(const float4*)(&Ws[kq+j][tx*4]);
        #pragma unroll
        for (int r=0;r<RM;++r){
          float xs = (j==0)?xv[r].x:(j==1)?xv[r].y:(j==2)?xv[r].z:xv[r].w;
          acc[r][0]=fmaf(xs,wv.x,acc[r][0]);
          acc[r][1]=fmaf(xs,wv.y,acc[r][1]);
          acc[r][2]=fmaf(xs,wv.z,acc[r][2]);
          acc[r][3]=fmaf(xs,wv.w,acc[r][3]);
        }
      }
    }
    __syncthreads();
  }
  #pragma unroll
  for (int r=0;r<RM;++r){
    int m = m0 + ty*RM + r;
    float4 h; h.x=acc[r][0];h.y=acc[r][1];h.z=acc[r][2];h.w=acc[r][3];
    stU4(H, (size_t)m*N + n0 + tx*4, h);
  }
}

// ---- fused per-graph CSR build (round-14 WIN kernel, unchanged)
__global__ __launch_bounds__(1024) void k_csr(const int* __restrict__ src0,
    const int* __restrict__ dst0, int* __restrict__ rowptr,
    int* __restrict__ col, float* __restrict__ dinv){
  __shared__ int ldeg[1024];
  __shared__ int ps[1024];
  __shared__ int lcur[1024];
  const int g = blockIdx.x, t = threadIdx.x;
  const int ebase = g*EPG_, nbase = g<<10;
  ldeg[t] = 0;
  __syncthreads();
  #pragma unroll
  for (int i=0;i<EPG_/1024;++i){
    int e = ebase + i*1024 + t;
    atomicAdd(&ldeg[dst0[e] - nbase], 1);
  }
  __syncthreads();
  int d = ldeg[t];
  ps[t] = d; __syncthreads();
  for (int o=1;o<1024;o<<=1){
    int v = (t>=o) ? ps[t-o] : 0;
    __syncthreads(); ps[t] += v; __syncthreads();
  }
  int excl = ps[t] - d;
  rowptr[nbase + t] = ebase + excl;
  lcur[t] = excl;
  dinv[nbase + t] = rsqrtf((float)d + 2.f);
  if (g == B_-1 && t == 1023) rowptr[M0_] = E_;
  __syncthreads();
  #pragma unroll
  for (int i=0;i<EPG_/1024;++i){
    int e = ebase + i*1024 + t;
    int dl = dst0[e] - nbase;
    int p = atomicAdd(&lcur[dl], 1);
    col[ebase + p] = src0[e];
  }
}

// ---- fused per-graph pool (round-14 WIN kernel, unchanged)
__global__ __launch_bounds__(1024) void k_pool(const float* __restrict__ score,
    int npg, int K, const int* __restrict__ prevOrig,
    const int* __restrict__ rowptr0, const int* __restrict__ col0,
    int* __restrict__ perm, float* __restrict__ vals,
    int* __restrict__ orig, int* __restrict__ rm, float* __restrict__ dinv){
  __shared__ float ss[1024]; __shared__ int si[1024];
  const int g = blockIdx.x, t = threadIdx.x;
  for (int i=t; i<1024; i+=npg) rm[(g<<10)+i] = -1;
  ss[t] = score[g*npg + t]; si[t] = t;
  __syncthreads();
  for (int k=2;k<=npg;k<<=1){
    for (int j=k>>1;j>0;j>>=1){
      int ixj = t ^ j;
      if (ixj > t){
        float s1=ss[t], s2=ss[ixj]; int i1=si[t], i2=si[ixj];
        bool aAfterB = (s1 < s2) || (s1==s2 && i1 > i2);
        bool sw = ((t & k)==0) ? aAfterB : !aAfterB;
        if (sw){ ss[t]=s2; si[t]=i2; ss[ixj]=s1; si[ixj]=i1; }
      }
      __syncthreads();
    }
  }
  int o = -1;
  if (t < K){
    int pl = g*npg + si[t];
    perm[g*K+t] = pl;
    vals[g*K+t] = ss[t];
    o = prevOrig ? prevOrig[pl] : pl;
    orig[g*K+t] = o;
    rm[o] = g*K + t;
  }
  __syncthreads();
  if (t < K){
    int beg = rowptr0[o], end = rowptr0[o+1];
    int d = 0;
    for (int j=beg;j<end;++j) d += (rm[col0[j]] >= 0) ? 1 : 0;
    dinv[g*K+t] = rsqrtf((float)d + 2.f);
  }
}

// ---- level-0 GCN aggregation (H bf16 in, OUT bf16); optional fused score
template<int F, bool SCORE>
__global__ __launch_bounds__(256) void k_gather(const int* __restrict__ rowptr,
    const int* __restrict__ col, const float* __restrict__ dinv,
    const unsigned short* __restrict__ H, const float* __restrict__ bias,
    unsigned short* __restrict__ OUT, int M,
    const float* __restrict__ p, float* __restrict__ score){
  constexpr int FQ = F/4;
  int i = blockIdx.x*256+threadIdx.x;
  if (i >= M*FQ) return;
  int n = i/FQ, q = i - (i/FQ)*FQ;
  int beg = rowptr[n], end = rowptr[n+1];
  float4 acc; acc.x=0.f;acc.y=0.f;acc.z=0.f;acc.w=0.f;
  for (int j=beg;j<end;++j){
    int s = col[j];
    float c = dinv[s];
    float4 h = ldU4(H, (size_t)s*F + q*4);
    acc.x=fmaf(c,h.x,acc.x); acc.y=fmaf(c,h.y,acc.y);
    acc.z=fmaf(c,h.z,acc.z); acc.w=fmaf(c,h.w,acc.w);
  }
  float dn = dinv[n];
  float sc = 2.f*dn*dn;
  float4 hn = ldU4(H, (size_t)n*F + q*4);
  float4 bv = *(const float4*)(bias + q*4);
  float4 o;
  o.x = eluf(fmaf(sc,hn.x,fmaf(dn,acc.x,bv.x)));
  o.y = eluf(fmaf(sc,hn.y,fmaf(dn,acc.y,bv.y)));
  o.z = eluf(fmaf(sc,hn.z,fmaf(dn,acc.z,bv.z)));
  o.w = eluf(fmaf(sc,hn.w,fmaf(dn,acc.w,bv.w)));
  stU4(OUT, (size_t)n*F + q*4, o);
  if (SCORE){
    float4 pv = *(const float4*)(p + q*4);
    float dot = o.x*pv.x + o.y*pv.y + o.z*pv.z + o.w*pv.w;
    float n2  = pv.x*pv.x + pv.y*pv.y + pv.z*pv.z + pv.w*pv.w;
    #pragma unroll
    for (int mk=FQ>>1; mk>0; mk>>=1){
      dot += __shfl_xor(dot, mk);
      n2  += __shfl_xor(n2,  mk);
    }
    if (q==0) score[n] = tanhf(dot * rsqrtf(n2));
  }
}

// ---- pooled-level GCN aggregation through rm filter (bf16 H/OUT)
template<int F, bool SCORE>
__global__ __launch_bounds__(256) void k_gather_rm(const int* __restrict__ orig,
    const int* __restrict__ rowptr0, const int* __restrict__ col0,
    const int* __restrict__ rm, const float* __restrict__ dinv,
    const unsigned short* __restrict__ H, const float* __restrict__ bias,
    unsigned short* __restrict__ OUT, int M,
    const float* __restrict__ p, float* __restrict__ score){
  constexpr int FQ = F/4;
  int i = blockIdx.x*256+threadIdx.x;
  if (i >= M*FQ) return;
  int n = i/FQ, q = i - (i/FQ)*FQ;
  int o = orig[n];
  int beg = rowptr0[o], end = rowptr0[o+1];
  float4 acc; acc.x=0.f;acc.y=0.f;acc.z=0.f;acc.w=0.f;
  for (int j=beg;j<end;++j){
    int s = rm[col0[j]];
    if (s >= 0){
      float c = dinv[s];
      float4 h = ldU4(H, (size_t)s*F + q*4);
      acc.x=fmaf(c,h.x,acc.x); acc.y=fmaf(c,h.y,acc.y);
      acc.z=fmaf(c,h.z,acc.z); acc.w=fmaf(c,h.w,acc.w);
    }
  }
  float dn = dinv[n];
  float sc = 2.f*dn*dn;
  float4 hn = ldU4(H, (size_t)n*F + q*4);
  float4 bv = *(const float4*)(bias + q*4);
  float4 ov;
  ov.x = eluf(fmaf(sc,hn.x,fmaf(dn,acc.x,bv.x)));
  ov.y = eluf(fmaf(sc,hn.y,fmaf(dn,acc.y,bv.y)));
  ov.z = eluf(fmaf(sc,hn.z,fmaf(dn,acc.z,bv.z)));
  ov.w = eluf(fmaf(sc,hn.w,fmaf(dn,acc.w,bv.w)));
  stU4(OUT, (size_t)n*F + q*4, ov);
  if (SCORE){
    float4 pv = *(const float4*)(p + q*4);
    float dot = ov.x*pv.x + ov.y*pv.y + ov.z*pv.z + ov.w*pv.w;
    float n2  = pv.x*pv.x + pv.y*pv.y + pv.z*pv.z + pv.w*pv.w;
    #pragma unroll
    for (int mk=FQ>>1; mk>0; mk>>=1){
      dot += __shfl_xor(dot, mk);
      n2  += __shfl_xor(n2,  mk);
    }
    if (q==0) score[n] = tanhf(dot * rsqrtf(n2));
  }
}

// per-graph global max/mean pool over (1024,32) bf16 x13, MLP head + log_softmax
__global__ void k_head(const unsigned short* __restrict__ x13, const float* __restrict__ Wl,
                       const float* __restrict__ Wc, const float* __restrict__ bc,
                       float* __restrict__ out){
  __shared__ float smax[256], ssum[256];
  __shared__ float gv[64], g2[64], logit[10];
  int g = blockIdx.x, t = threadIdx.x;
  int f = t & 31, r0 = t >> 5;
  float mx = -3.4e38f, sm = 0.f;
  const unsigned short* base = x13 + (size_t)g*N_*32;
  for (int r=r0; r<N_; r+=8){ float v = bf2f(base[r*32+f]); mx = fmaxf(mx,v); sm += v; }
  smax[t]=mx; ssum[t]=sm; __syncthreads();
  if (t<128){ smax[t]=fmaxf(smax[t],smax[t+128]); ssum[t]+=ssum[t+128]; } __syncthreads();
  if (t<64){ smax[t]=fmaxf(smax[t],smax[t+64]); ssum[t]+=ssum[t+64]; } __syncthreads();
  if (t<32){
    float m2 = fmaxf(smax[t],smax[t+32]); float s2 = ssum[t]+ssum[t+32];
    gv[t] = eluf(m2); gv[32+t] = eluf(s2 * (1.f/N_));
  }
  __syncthreads();
  if (t<64){
    float acc=0.f;
    #pragma unroll
    for (int i2=0;i2<64;++i2) acc = fmaf(gv[i2], Wl[i2*64+t], acc);
    g2[t] = eluf(acc);
  }
  __syncthreads();
  if (t<10){
    float acc = bc[t];
    #pragma unroll
    for (int j=0;j<64;++j) acc = fmaf(g2[j], Wc[j*10+t], acc);
    logit[t] = acc;
  }
  __syncthreads();
  if (t==0){
    float m=-3.4e38f; for (int c=0;c<10;++c) m=fmaxf(m,logit[c]);
    float s=0.f; for (int c=0;c<10;++c) s += expf(logit[c]-m);
    float lse = m + logf(s);
    for (int c=0;c<10;++c) out[g*10+c] = logit[c]-lse;
  }
}

extern "C" void kernel_launch(void* const* d_in, const int* in_sizes, int n_in,
                              void* d_out, int out_size, void* d_ws, size_t ws_size,
                              hipStream_t stream){
  const float* x  = (const float*)d_in[0];
  const float* W1 = (const float*)d_in[1];
  const float* b1 = (const float*)d_in[2];
  const float* p1 = (const float*)d_in[3];
  const float* W2 = (const float*)d_in[4];
  const float* b2 = (const float*)d_in[5];
  const float* p2 = (const float*)d_in[6];
  const float* W3 = (const float*)d_in[7];
  const float* b3 = (const float*)d_in[8];
  const float* p3 = (const float*)d_in[9];
  const float* W4 = (const float*)d_in[10];
  const float* b4 = (const float*)d_in[11];
  const float* W5 = (const float*)d_in[12];
  const float* b5 = (const float*)d_in[13];
  const float* W6 = (const float*)d_in[14];
  const float* b6 = (const float*)d_in[15];
  const float* W7 = (const float*)d_in[16];
  const float* b7 = (const float*)d_in[17];
  const float* Wl = (const float*)d_in[18];
  const float* Wc = (const float*)d_in[19];
  const float* bc = (const float*)d_in[20];
  const int* src0 = (const int*)d_in[21];
  const int* dst0 = (const int*)d_in[22];
  float* out = (float*)d_out;

  char* wsp = (char*)d_ws;
  size_t off = 0;
  auto alloc = [&](size_t bytes)->char*{
    char* p = wsp + off;
    off += (bytes + 255) & ~(size_t)255;
    return p;
  };
  unsigned short* bufA = (unsigned short*)alloc((size_t)2097152*2);  // x1 / x13 (bf16)
  unsigned short* bufB = (unsigned short*)alloc((size_t)2097152*2);  // x3
  unsigned short* bufC = (unsigned short*)alloc((size_t)2097152*2);  // x5 / x11
  unsigned short* bufD = (unsigned short*)alloc((size_t)2097152*2);  // x7 / x9
  unsigned short* bufH = (unsigned short*)alloc((size_t)2097152*2);  // pre-norm H (bf16)
  float* score= (float*)alloc((size_t)M0_*4);
  float* vals2= (float*)alloc((size_t)M1_*4);
  float* vals4= (float*)alloc((size_t)M2_*4);
  float* vals6= (float*)alloc((size_t)M3_*4);
  int* idx2 = (int*)alloc((size_t)M1_*4);   // level2 -> level0 (perm AND orig)
  int* idx4 = (int*)alloc((size_t)M2_*4);   // level4 -> level2 (perm)
  int* idx6 = (int*)alloc((size_t)M3_*4);   // level6 -> level4 (perm)
  int* orig4 = (int*)alloc((size_t)M2_*4);  // level4 -> level0
  int* orig6 = (int*)alloc((size_t)M3_*4);  // level6 -> level0
  int* rm02 = (int*)alloc((size_t)M0_*4);
  int* rm04 = (int*)alloc((size_t)M0_*4);
  int* rm06 = (int*)alloc((size_t)M0_*4);
  int* col0 = (int*)alloc((size_t)E_*4);
  int* rowptr0 = (int*)alloc((size_t)(M0_+1)*4);
  float* dinv0 = (float*)alloc((size_t)M0_*4);
  float* dinv2 = (float*)alloc((size_t)M1_*4);
  float* dinv4 = (float*)alloc((size_t)M2_*4);
  float* dinv6 = (float*)alloc((size_t)M3_*4);

  auto NB = [](int total){ return (total+255)/256; };

  // ---- level-0 CSR: ONE fused per-graph kernel
  k_csr<<<B_,1024,0,stream>>>(src0, dst0, rowptr0, col0, dinv0);

  // ---- layer 1: H1 = x@W1; x1 = gather (bufA) + fused score1
  k_mm<128,32,0><<<dim3(M0_/128,1),256,0,stream>>>(x, nullptr, W1, bufH, M0_, 128, 32,
      nullptr,nullptr,nullptr,nullptr,nullptr,0);
  k_gather<32,true><<<NB(M0_*8),256,0,stream>>>(rowptr0, col0, dinv0, bufH, b1, bufA, M0_, p1, score);

  // ---- pool 1
  k_pool<<<B_,1024,0,stream>>>(score, 1024, K1_, nullptr, rowptr0, col0,
      idx2, vals2, idx2, rm02, dinv2);

  // ---- layer 2 (fused pool staging) -> x3 (bufB) + score2
  k_mm<64,64,1><<<dim3(M1_/64,1),256,0,stream>>>(nullptr, bufA, W2, bufH, M1_, 32, 64,
      idx2, vals2, nullptr,nullptr,nullptr,0);
  k_gather_rm<64,true><<<NB(M1_*16),256,0,stream>>>(idx2, rowptr0, col0, rm02, dinv2, bufH, b2, bufB, M1_, p2, score);

  // ---- pool 2
  k_pool<<<B_,512,0,stream>>>(score, 512, K2_, idx2, rowptr0, col0,
      idx4, vals4, orig4, rm04, dinv4);

  // ---- layer 3 -> x5 (bufC) + score3
  k_mm<64,64,1><<<dim3(M2_/64,2),256,0,stream>>>(nullptr, bufB, W3, bufH, M2_, 64, 128,
      idx4, vals4, nullptr,nullptr,nullptr,0);
  k_gather_rm<128,true><<<NB(M2_*32),256,0,stream>>>(orig4, rowptr0, col0, rm04, dinv4, bufH, b3, bufC, M2_, p3, score);

  // ---- pool 3
  k_pool<<<B_,256,0,stream>>>(score, 256, K3_, orig4, rowptr0, col0,
      idx6, vals6, orig6, rm06, dinv6);

  // ---- layer 4 -> x7 (bufD)
  k_mm<64,64,1><<<dim3(M3_/64,4),256,0,stream>>>(nullptr, bufC, W4, bufH, M3_, 128, 256,
      idx6, vals6, nullptr,nullptr,nullptr,0);
  k_gather_rm<256,false><<<NB(M3_*64),256,0,stream>>>(orig6, rowptr0, col0, rm06, dinv6, bufH, b4, bufD, M3_, nullptr, nullptr);

  // ---- layer 5 (fused concat staging) -> x9 (bufD)
  k_mm<64,64,2><<<dim3(M2_/64,2),256,0,stream>>>(nullptr, bufC, W5, bufH, M2_, 384, 128,
      nullptr,nullptr, bufD, orig4, rm06, 64);
  k_gather_rm<128,false><<<NB(M2_*32),256,0,stream>>>(orig4, rowptr0, col0, rm04, dinv4, bufH, b5, bufD, M2_, nullptr, nullptr);

  // ---- layer 6 -> x11 (bufC)
  k_mm<64,64,2><<<dim3(M1_/64,1),256,0,stream>>>(nullptr, bufB, W6, bufH, M1_, 192, 64,
      nullptr,nullptr, bufD, idx2, rm04, 32);
  k_gather_rm<64,false><<<NB(M1_*16),256,0,stream>>>(idx2, rowptr0, col0, rm02, dinv2, bufH, b6, bufC, M1_, nullptr, nullptr);

  // ---- layer 7 -> x13 (bufA)
  k_mm<128,32,2><<<dim3(M0_/128,1),256,0,stream>>>(nullptr, bufA, W7, bufH, M0_, 96, 32,
      nullptr,nullptr, bufC, nullptr, rm02, 16);
  k_gather<32,false><<<NB(M0_*8),256,0,stream>>>(rowptr0, col0, dinv0, bufH, b7, bufA, M0_, nullptr, nullptr);

  // ---- head
  k_head<<<B_,256,0,stream>>>(bufA, Wl, Wc, bc, out);

  (void)in_sizes; (void)n_in; (void)out_size; (void)ws_size;
}